// Round 1
// baseline (1019.378 us; speedup 1.0000x reference)
//
#include <hip/hip_runtime.h>
#include <cstdint>
#include <cstddef>

#define BN_EPS 1e-5f

// ---------------- graph prep ----------------

__global__ __launch_bounds__(256) void k_count(const int* __restrict__ dst, int e, int* __restrict__ cnt) {
  int i = blockIdx.x * 256 + threadIdx.x;
  if (i < e) atomicAdd(&cnt[dst[i]], 1);
}

__global__ __launch_bounds__(256) void k_dinv(const int* __restrict__ cnt, float* __restrict__ dinv, int n) {
  int i = blockIdx.x * 256 + threadIdx.x;
  if (i < n) dinv[i] = rsqrtf((float)cnt[i] + 1.0f);
}

__global__ __launch_bounds__(256) void k_scan1(const int* __restrict__ cnt, int n, int* __restrict__ bsum) {
  __shared__ int ls[256];
  int i = blockIdx.x * 256 + threadIdx.x;
  ls[threadIdx.x] = (i < n) ? cnt[i] : 0;
  __syncthreads();
  for (int s = 128; s > 0; s >>= 1) {
    if (threadIdx.x < s) ls[threadIdx.x] += ls[threadIdx.x + s];
    __syncthreads();
  }
  if (threadIdx.x == 0) bsum[blockIdx.x] = ls[0];
}

__global__ __launch_bounds__(1024) void k_scan2(int* bsum, int nb) {
  __shared__ int ls[1024];
  int v = (threadIdx.x < nb) ? bsum[threadIdx.x] : 0;
  ls[threadIdx.x] = v;
  __syncthreads();
  for (int off = 1; off < 1024; off <<= 1) {
    int t = (threadIdx.x >= off) ? ls[threadIdx.x - off] : 0;
    __syncthreads();
    ls[threadIdx.x] += t;
    __syncthreads();
  }
  if (threadIdx.x < nb) bsum[threadIdx.x] = ls[threadIdx.x] - v;  // exclusive
}

__global__ __launch_bounds__(256) void k_scan3(const int* __restrict__ cnt, int n, const int* __restrict__ bsum,
                                               int* __restrict__ rowptr, int etot) {
  __shared__ int ls[256];
  int i = blockIdx.x * 256 + threadIdx.x;
  int v = (i < n) ? cnt[i] : 0;
  ls[threadIdx.x] = v;
  __syncthreads();
  for (int off = 1; off < 256; off <<= 1) {
    int t = (threadIdx.x >= off) ? ls[threadIdx.x - off] : 0;
    __syncthreads();
    ls[threadIdx.x] += t;
    __syncthreads();
  }
  if (i < n) rowptr[i] = bsum[blockIdx.x] + ls[threadIdx.x] - v;
  if (i == n - 1) rowptr[n] = etot;
}

__global__ __launch_bounds__(256) void k_fill(const int* __restrict__ src, const int* __restrict__ dst, int e,
                                              const int* __restrict__ rowptr, int* __restrict__ cursor,
                                              int* __restrict__ col) {
  int i = blockIdx.x * 256 + threadIdx.x;
  if (i < e) {
    int d = dst[i];
    int p = atomicAdd(&cursor[d], 1);
    col[rowptr[d] + p] = src[i];
  }
}

// ---------------- GEMMs (f32, vector ALU) ----------------
// C[n,128] = A[n,128] @ B[128,128].  Tile 128x128, 8x8 microtile, 256 thr.
__global__ __launch_bounds__(256) void k_gemm128(const float* __restrict__ A, const float* __restrict__ B,
                                                 float* __restrict__ C, int n) {
  __shared__ float As[128][33];   // [m][k], +1 pad -> conflict-free strided reads
  __shared__ float Bs[32][132];   // [k][n]
  int tid = threadIdx.x;
  int row0 = blockIdx.x * 128;
  int tx = tid & 15, ty = tid >> 4;
  float acc[8][8];
#pragma unroll
  for (int i = 0; i < 8; ++i)
#pragma unroll
    for (int j = 0; j < 8; ++j) acc[i][j] = 0.f;

  for (int kt = 0; kt < 128; kt += 32) {
#pragma unroll
    for (int rr = 0; rr < 128; rr += 32) {
      int r = rr + (tid >> 3);
      int kc = (tid & 7) * 4;
      int gr = row0 + r;
      float4 v = make_float4(0.f, 0.f, 0.f, 0.f);
      if (gr < n) v = *(const float4*)&A[(size_t)gr * 128 + kt + kc];
      As[r][kc] = v.x; As[r][kc + 1] = v.y; As[r][kc + 2] = v.z; As[r][kc + 3] = v.w;
    }
#pragma unroll
    for (int rr = 0; rr < 32; rr += 8) {
      int k = rr + (tid >> 5);
      int c = (tid & 31) * 4;
      *(float4*)&Bs[k][c] = *(const float4*)&B[(size_t)(kt + k) * 128 + c];
    }
    __syncthreads();
#pragma unroll
    for (int k = 0; k < 32; ++k) {
      float a[8], b[8];
#pragma unroll
      for (int i = 0; i < 8; ++i) a[i] = As[ty * 8 + i][k];
      *(float4*)&b[0] = *(const float4*)&Bs[k][tx * 4];
      *(float4*)&b[4] = *(const float4*)&Bs[k][64 + tx * 4];
#pragma unroll
      for (int i = 0; i < 8; ++i)
#pragma unroll
        for (int j = 0; j < 8; ++j) acc[i][j] += a[i] * b[j];
    }
    __syncthreads();
  }
#pragma unroll
  for (int i = 0; i < 8; ++i) {
    int gr = row0 + ty * 8 + i;
    if (gr < n) {
      float4 v0 = make_float4(acc[i][0], acc[i][1], acc[i][2], acc[i][3]);
      float4 v1 = make_float4(acc[i][4], acc[i][5], acc[i][6], acc[i][7]);
      *(float4*)&C[(size_t)gr * 128 + tx * 4] = v0;
      *(float4*)&C[(size_t)gr * 128 + 64 + tx * 4] = v1;
    }
  }
}

// C[n,64] = [A0|A1|A2] (each [n,128]) @ B[384,64]
__global__ __launch_bounds__(256) void k_gemm3(const float* __restrict__ A0, const float* __restrict__ A1,
                                               const float* __restrict__ A2, const float* __restrict__ B,
                                               float* __restrict__ C, int n) {
  __shared__ float As[128][33];
  __shared__ float Bs[32][68];
  int tid = threadIdx.x;
  int row0 = blockIdx.x * 128;
  int tx = tid & 15, ty = tid >> 4;
  float acc[8][4];
#pragma unroll
  for (int i = 0; i < 8; ++i)
#pragma unroll
    for (int j = 0; j < 4; ++j) acc[i][j] = 0.f;

  for (int kt = 0; kt < 384; kt += 32) {
    const float* A = (kt < 128) ? A0 : (kt < 256 ? A1 : A2);
    int kl = kt & 127;
#pragma unroll
    for (int rr = 0; rr < 128; rr += 32) {
      int r = rr + (tid >> 3);
      int kc = (tid & 7) * 4;
      int gr = row0 + r;
      float4 v = make_float4(0.f, 0.f, 0.f, 0.f);
      if (gr < n) v = *(const float4*)&A[(size_t)gr * 128 + kl + kc];
      As[r][kc] = v.x; As[r][kc + 1] = v.y; As[r][kc + 2] = v.z; As[r][kc + 3] = v.w;
    }
#pragma unroll
    for (int rr = 0; rr < 32; rr += 16) {
      int k = rr + (tid >> 4);
      int c = (tid & 15) * 4;
      *(float4*)&Bs[k][c] = *(const float4*)&B[(size_t)(kt + k) * 64 + c];
    }
    __syncthreads();
#pragma unroll
    for (int k = 0; k < 32; ++k) {
      float a[8], b[4];
#pragma unroll
      for (int i = 0; i < 8; ++i) a[i] = As[ty * 8 + i][k];
      *(float4*)&b[0] = *(const float4*)&Bs[k][tx * 4];
#pragma unroll
      for (int i = 0; i < 8; ++i)
#pragma unroll
        for (int j = 0; j < 4; ++j) acc[i][j] += a[i] * b[j];
    }
    __syncthreads();
  }
#pragma unroll
  for (int i = 0; i < 8; ++i) {
    int gr = row0 + ty * 8 + i;
    if (gr < n) {
      float4 v0 = make_float4(acc[i][0], acc[i][1], acc[i][2], acc[i][3]);
      *(float4*)&C[(size_t)gr * 64 + tx * 4] = v0;
    }
  }
}

// ---------------- aggregation (CSR gather-sum) + bias + relu ----------------
template <int F>
__global__ __launch_bounds__(256) void k_agg(const float* __restrict__ t, const int* __restrict__ rowptr,
                                             const int* __restrict__ col, const float* __restrict__ dinv,
                                             const float* __restrict__ bias, float* __restrict__ out, int n) {
  const int RPB = 256 / F;
  int r = blockIdx.x * RPB + threadIdx.x / F;
  int f = threadIdx.x & (F - 1);
  if (r >= n) return;
  float di = dinv[r];
  float acc = di * t[(size_t)r * F + f];  // self loop (x di again below -> di^2)
  int e0 = rowptr[r], e1 = rowptr[r + 1];
  int e = e0;
  for (; e + 1 < e1; e += 2) {
    int s0 = col[e], s1 = col[e + 1];
    float w0 = dinv[s0], w1 = dinv[s1];
    acc += w0 * t[(size_t)s0 * F + f];
    acc += w1 * t[(size_t)s1 * F + f];
  }
  if (e < e1) {
    int s0 = col[e];
    acc += dinv[s0] * t[(size_t)s0 * F + f];
  }
  float v = acc * di + bias[f];
  out[(size_t)r * F + f] = fmaxf(v, 0.f);
}

// ---------------- batchnorm ----------------
__global__ __launch_bounds__(256) void k_bnstats(const float* __restrict__ h, int n, float* __restrict__ sums) {
  __shared__ float ls[256], ls2[256];
  int f = threadIdx.x & 127;
  int half = threadIdx.x >> 7;
  int r0 = blockIdx.x * 256;
  int rend = min(r0 + 256, n);
  float s = 0.f, s2 = 0.f;
  for (int r = r0 + half; r < rend; r += 2) {
    float v = h[(size_t)r * 128 + f];
    s += v;
    s2 += v * v;
  }
  ls[threadIdx.x] = s;
  ls2[threadIdx.x] = s2;
  __syncthreads();
  if (half == 0) {
    atomicAdd(&sums[f], s + ls[128 + f]);
    atomicAdd(&sums[128 + f], s2 + ls2[128 + f]);
  }
}

__global__ void k_bnfinal(const float* __restrict__ sums, const float* __restrict__ gamma,
                          const float* __restrict__ beta, float* __restrict__ ss, int n) {
  int f = threadIdx.x;
  float invN = 1.f / (float)n;
  float m = sums[f] * invN;
  float var = sums[128 + f] * invN - m * m;
  float sc = gamma[f] * rsqrtf(var + BN_EPS);
  ss[f] = sc;
  ss[128 + f] = beta[f] - m * sc;
}

__global__ __launch_bounds__(256) void k_bnapply(float* __restrict__ h, int n, const float* __restrict__ ss) {
  size_t total = (size_t)n * 32;  // n*128/4 float4s
  for (size_t i = (size_t)blockIdx.x * 256 + threadIdx.x; i < total; i += (size_t)gridDim.x * 256) {
    int f = (int)(i & 31) * 4;
    float4 v = *(float4*)&h[i * 4];
    v.x = v.x * ss[f + 0] + ss[128 + f + 0];
    v.y = v.y * ss[f + 1] + ss[128 + f + 1];
    v.z = v.z * ss[f + 2] + ss[128 + f + 2];
    v.w = v.w * ss[f + 3] + ss[128 + f + 3];
    *(float4*)&h[i * 4] = v;
  }
}

// ---------------- launch ----------------
extern "C" void kernel_launch(void* const* d_in, const int* in_sizes, int n_in,
                              void* d_out, int out_size, void* d_ws, size_t ws_size,
                              hipStream_t stream) {
  const float* x    = (const float*)d_in[0];
  const int*   ei   = (const int*)d_in[1];
  const float* W1   = (const float*)d_in[2];
  const float* b1   = (const float*)d_in[3];
  const float* W2   = (const float*)d_in[4];
  const float* b2   = (const float*)d_in[5];
  const float* Wout = (const float*)d_in[6];
  const float* bout = (const float*)d_in[7];
  const float* gamma= (const float*)d_in[8];
  const float* beta = (const float*)d_in[9];
  float* out = (float*)d_out;

  const int n = in_sizes[0] / 128;
  const int e = in_sizes[1] / 2;
  const int* src = ei;
  const int* dst = ei + e;

  char* ws = (char*)d_ws;
  size_t off = 0;
  auto alloc = [&](size_t bytes) -> void* {
    void* p = ws + off;
    off += (bytes + 255) & ~(size_t)255;
    return p;
  };
  int*   cnt    = (int*)alloc((size_t)n * 4);
  int*   cursor = (int*)alloc((size_t)n * 4);
  int*   rowptr = (int*)alloc(((size_t)n + 1) * 4);
  int*   bsum   = (int*)alloc(1024 * 4);
  float* dinv   = (float*)alloc((size_t)n * 4);
  float* sums   = (float*)alloc(256 * 4);
  float* ss     = (float*)alloc(256 * 4);
  int*   col    = (int*)alloc((size_t)e * 4);
  float* t      = (float*)alloc((size_t)n * 128 * 4);
  float* h1     = (float*)alloc((size_t)n * 128 * 4);
  float* h2     = (float*)alloc((size_t)n * 128 * 4);

  hipMemsetAsync(cnt, 0, (size_t)n * 4, stream);
  hipMemsetAsync(cursor, 0, (size_t)n * 4, stream);
  hipMemsetAsync(sums, 0, 256 * 4, stream);

  int nbE = (e + 255) / 256;
  int nbN = (n + 255) / 256;
  k_count<<<nbE, 256, 0, stream>>>(dst, e, cnt);
  k_dinv<<<nbN, 256, 0, stream>>>(cnt, dinv, n);
  k_scan1<<<nbN, 256, 0, stream>>>(cnt, n, bsum);
  k_scan2<<<1, 1024, 0, stream>>>(bsum, nbN);
  k_scan3<<<nbN, 256, 0, stream>>>(cnt, n, bsum, rowptr, e);
  k_fill<<<nbE, 256, 0, stream>>>(src, dst, e, rowptr, cursor, col);

  int nbG = (n + 127) / 128;

  // layer 1
  k_gemm128<<<nbG, 256, 0, stream>>>(x, W1, t, n);
  k_agg<128><<<(n + 1) / 2, 256, 0, stream>>>(t, rowptr, col, dinv, b1, h1, n);
  k_bnstats<<<nbN, 256, 0, stream>>>(h1, n, sums);
  k_bnfinal<<<1, 128, 0, stream>>>(sums, gamma, beta, ss, n);
  k_bnapply<<<2048, 256, 0, stream>>>(h1, n, ss);

  // layer 2
  hipMemsetAsync(sums, 0, 256 * 4, stream);
  k_gemm128<<<nbG, 256, 0, stream>>>(h1, W2, t, n);
  k_agg<128><<<(n + 1) / 2, 256, 0, stream>>>(t, rowptr, col, dinv, b2, h2, n);
  k_bnstats<<<nbN, 256, 0, stream>>>(h2, n, sums);
  k_bnfinal<<<1, 128, 0, stream>>>(sums, gamma, beta, ss, n);
  k_bnapply<<<2048, 256, 0, stream>>>(h2, n, ss);

  // layer 3 (skip-concat GEMM then aggregate straight into d_out)
  k_gemm3<<<nbG, 256, 0, stream>>>(x, h1, h2, Wout, t, n);
  k_agg<64><<<(n + 3) / 4, 256, 0, stream>>>(t, rowptr, col, dinv, bout, out, n);
}

// Round 2
// 568.846 us; speedup vs baseline: 1.7920x; 1.7920x over previous
//
#include <hip/hip_runtime.h>
#include <cstdint>
#include <cstddef>

#define BN_EPS 1e-5f

typedef __attribute__((ext_vector_type(8))) short  bf16x8;   // MFMA A/B frag (8 bf16)
typedef __attribute__((ext_vector_type(4))) float  f32x4;    // MFMA C/D frag
typedef __attribute__((ext_vector_type(8))) unsigned short ushort8;

__device__ __forceinline__ float bf2f(unsigned short u) {
  union { unsigned int i; float f; } c; c.i = ((unsigned int)u) << 16; return c.f;
}
__device__ __forceinline__ unsigned short f2bf(float f) {
  union { float f; unsigned int i; } c; c.f = f;
  unsigned int u = c.i;
  return (unsigned short)((u + 0x7FFFu + ((u >> 16) & 1u)) >> 16);  // RNE
}

// ---------------- graph prep ----------------

__global__ __launch_bounds__(256) void k_count(const int* __restrict__ dst, int e, int* __restrict__ cnt) {
  int i = blockIdx.x * 256 + threadIdx.x;
  if (i < e) atomicAdd(&cnt[dst[i]], 1);
}

__global__ __launch_bounds__(256) void k_dinv(const int* __restrict__ cnt, float* __restrict__ dinv, int n) {
  int i = blockIdx.x * 256 + threadIdx.x;
  if (i < n) dinv[i] = rsqrtf((float)cnt[i] + 1.0f);
}

__global__ __launch_bounds__(256) void k_scan1(const int* __restrict__ cnt, int n, int* __restrict__ bsum) {
  __shared__ int ls[256];
  int i = blockIdx.x * 256 + threadIdx.x;
  ls[threadIdx.x] = (i < n) ? cnt[i] : 0;
  __syncthreads();
  for (int s = 128; s > 0; s >>= 1) {
    if (threadIdx.x < s) ls[threadIdx.x] += ls[threadIdx.x + s];
    __syncthreads();
  }
  if (threadIdx.x == 0) bsum[blockIdx.x] = ls[0];
}

__global__ __launch_bounds__(1024) void k_scan2(int* bsum, int nb) {
  __shared__ int ls[1024];
  int v = (threadIdx.x < nb) ? bsum[threadIdx.x] : 0;
  ls[threadIdx.x] = v;
  __syncthreads();
  for (int off = 1; off < 1024; off <<= 1) {
    int t = (threadIdx.x >= off) ? ls[threadIdx.x - off] : 0;
    __syncthreads();
    ls[threadIdx.x] += t;
    __syncthreads();
  }
  if (threadIdx.x < nb) bsum[threadIdx.x] = ls[threadIdx.x] - v;  // exclusive
}

__global__ __launch_bounds__(256) void k_scan3(const int* __restrict__ cnt, int n, const int* __restrict__ bsum,
                                               int* __restrict__ rowptr, int etot) {
  __shared__ int ls[256];
  int i = blockIdx.x * 256 + threadIdx.x;
  int v = (i < n) ? cnt[i] : 0;
  ls[threadIdx.x] = v;
  __syncthreads();
  for (int off = 1; off < 256; off <<= 1) {
    int t = (threadIdx.x >= off) ? ls[threadIdx.x - off] : 0;
    __syncthreads();
    ls[threadIdx.x] += t;
    __syncthreads();
  }
  if (i < n) rowptr[i] = bsum[blockIdx.x] + ls[threadIdx.x] - v;
  if (i == n - 1) rowptr[n] = etot;
}

__global__ __launch_bounds__(256) void k_fill(const int* __restrict__ src, const int* __restrict__ dst, int e,
                                              const int* __restrict__ rowptr, int* __restrict__ cursor,
                                              int* __restrict__ col) {
  int i = blockIdx.x * 256 + threadIdx.x;
  if (i < e) {
    int d = dst[i];
    int p = atomicAdd(&cursor[d], 1);
    col[rowptr[d] + p] = src[i];
  }
}

// ---------------- weight convert + transpose (f32 [K][N] -> bf16 [N][K]) ----------------
__global__ __launch_bounds__(256) void k_cvtw(const float* __restrict__ W1, const float* __restrict__ W2,
                                              const float* __restrict__ W3,
                                              unsigned short* __restrict__ Wt1, unsigned short* __restrict__ Wt2,
                                              unsigned short* __restrict__ Wt3) {
  int b = blockIdx.x, t = threadIdx.x;
  if (b < 64) {
    int idx = b * 256 + t; int k = idx >> 7, c = idx & 127;
    Wt1[c * 128 + k] = f2bf(W1[idx]);
  } else if (b < 128) {
    int idx = (b - 64) * 256 + t; int k = idx >> 7, c = idx & 127;
    Wt2[c * 128 + k] = f2bf(W2[idx]);
  } else {
    int idx = (b - 128) * 256 + t; int k = idx >> 6, c = idx & 63;   // [384][64]
    Wt3[c * 384 + k] = f2bf(W3[idx]);
  }
}

// ---------------- MFMA GEMM: C[n,128](bf16) = A[n,128] @ Wt^T, K=128 ----------------
// Wt stored [col][k] bf16. LDS XOR swizzle: byte ^= (row&7)<<4 (both write & read sides).
template <int SRC_F32>
__global__ __launch_bounds__(256) void k_gemm128(const void* __restrict__ Ap, const unsigned short* __restrict__ Bt,
                                                 unsigned short* __restrict__ C, int n) {
  __shared__ unsigned short As[128 * 128];
  __shared__ unsigned short Bs[128 * 128];
  const int tid = threadIdx.x;
  const int row0 = blockIdx.x * 128;

  // stage B (Wt rows = output cols), 2 threads/row, 8 x 16B chunks each
  {
    int colr = tid >> 1;
    int cbase = (tid & 1) * 8;
#pragma unroll
    for (int i = 0; i < 8; ++i) {
      int c16 = (cbase + i) * 16;
      int dst = colr * 256 + (c16 ^ ((colr & 7) << 4));
      ushort8 v = *reinterpret_cast<const ushort8*>(Bt + colr * 128 + (c16 >> 1));
      *reinterpret_cast<ushort8*>((char*)Bs + dst) = v;
    }
  }
  // stage A rows row0..row0+127
  {
    int r = tid >> 1;
    int gr = row0 + r;
    int cbase = (tid & 1) * 8;
#pragma unroll
    for (int i = 0; i < 8; ++i) {
      int c16 = (cbase + i) * 16;
      int dst = r * 256 + (c16 ^ ((r & 7) << 4));
      ushort8 v = (ushort8)0;
      if (SRC_F32) {
        const float* A = (const float*)Ap;
        if (gr < n) {
          f32x4 v0 = *reinterpret_cast<const f32x4*>(A + (size_t)gr * 128 + (c16 >> 1));
          f32x4 v1 = *reinterpret_cast<const f32x4*>(A + (size_t)gr * 128 + (c16 >> 1) + 4);
#pragma unroll
          for (int j = 0; j < 4; ++j) { v[j] = f2bf(v0[j]); v[4 + j] = f2bf(v1[j]); }
        }
      } else {
        const unsigned short* A = (const unsigned short*)Ap;
        if (gr < n) v = *reinterpret_cast<const ushort8*>(A + (size_t)gr * 128 + (c16 >> 1));
      }
      *reinterpret_cast<ushort8*>((char*)As + dst) = v;
    }
  }
  __syncthreads();

  const int wv = tid >> 6;
  const int l = tid & 63;
  const int lr = l & 15;
  const int lk = l >> 4;

  f32x4 acc[2][8];
#pragma unroll
  for (int mi = 0; mi < 2; ++mi)
#pragma unroll
    for (int ni = 0; ni < 8; ++ni) acc[mi][ni] = (f32x4)0.f;

#pragma unroll
  for (int kt = 0; kt < 4; ++kt) {
    int kbyte = kt * 64 + lk * 16;
    bf16x8 aF[2], bF[8];
#pragma unroll
    for (int mi = 0; mi < 2; ++mi) {
      int r = wv * 32 + mi * 16 + lr;
      aF[mi] = *reinterpret_cast<bf16x8*>((char*)As + r * 256 + (kbyte ^ ((r & 7) << 4)));
    }
#pragma unroll
    for (int ni = 0; ni < 8; ++ni) {
      int c = ni * 16 + lr;
      bF[ni] = *reinterpret_cast<bf16x8*>((char*)Bs + c * 256 + (kbyte ^ ((c & 7) << 4)));
    }
#pragma unroll
    for (int mi = 0; mi < 2; ++mi)
#pragma unroll
      for (int ni = 0; ni < 8; ++ni)
        acc[mi][ni] = __builtin_amdgcn_mfma_f32_16x16x32_bf16(aF[mi], bF[ni], acc[mi][ni], 0, 0, 0);
  }

#pragma unroll
  for (int mi = 0; mi < 2; ++mi)
#pragma unroll
    for (int ni = 0; ni < 8; ++ni)
#pragma unroll
      for (int i = 0; i < 4; ++i) {
        int gr = row0 + wv * 32 + mi * 16 + lk * 4 + i;
        int gc = ni * 16 + lr;
        if (gr < n) C[(size_t)gr * 128 + gc] = f2bf(acc[mi][ni][i]);
      }
}

// ---------------- MFMA GEMM3: C[n,64](bf16) = [x | h1bn | h2bn] @ Wt3^T, K=384 ----------------
__global__ __launch_bounds__(256) void k_gemm3(const float* __restrict__ x, const unsigned short* __restrict__ h1,
                                               const unsigned short* __restrict__ h2,
                                               const unsigned short* __restrict__ Bt3,
                                               unsigned short* __restrict__ C, int n) {
  __shared__ unsigned short As[128 * 128];   // 32KB, restaged per K-chunk
  __shared__ unsigned short Bs[64 * 384];    // 48KB, staged once
  const int tid = threadIdx.x;
  const int row0 = blockIdx.x * 128;

  // stage Bs: 4 threads/col, 12 x 16B chunks each (row stride 768B)
  {
    int colr = tid >> 2;
    int cb = tid & 3;
#pragma unroll
    for (int i = 0; i < 12; ++i) {
      int c16 = (cb + 4 * i) * 16;
      int dst = colr * 768 + (c16 ^ ((colr & 7) << 4));
      ushort8 v = *reinterpret_cast<const ushort8*>(Bt3 + colr * 384 + (c16 >> 1));
      *reinterpret_cast<ushort8*>((char*)Bs + dst) = v;
    }
  }

  const int wv = tid >> 6;
  const int l = tid & 63;
  const int lr = l & 15;
  const int lk = l >> 4;

  f32x4 acc[2][4];
#pragma unroll
  for (int mi = 0; mi < 2; ++mi)
#pragma unroll
    for (int ni = 0; ni < 4; ++ni) acc[mi][ni] = (f32x4)0.f;

  for (int ch = 0; ch < 3; ++ch) {
    if (ch) __syncthreads();
    // stage A chunk
    {
      int r = tid >> 1;
      int gr = row0 + r;
      int cbase = (tid & 1) * 8;
#pragma unroll
      for (int i = 0; i < 8; ++i) {
        int c16 = (cbase + i) * 16;
        int dst = r * 256 + (c16 ^ ((r & 7) << 4));
        ushort8 v = (ushort8)0;
        if (gr < n) {
          if (ch == 0) {
            f32x4 v0 = *reinterpret_cast<const f32x4*>(x + (size_t)gr * 128 + (c16 >> 1));
            f32x4 v1 = *reinterpret_cast<const f32x4*>(x + (size_t)gr * 128 + (c16 >> 1) + 4);
#pragma unroll
            for (int j = 0; j < 4; ++j) { v[j] = f2bf(v0[j]); v[4 + j] = f2bf(v1[j]); }
          } else {
            const unsigned short* A = (ch == 1) ? h1 : h2;
            v = *reinterpret_cast<const ushort8*>(A + (size_t)gr * 128 + (c16 >> 1));
          }
        }
        *reinterpret_cast<ushort8*>((char*)As + dst) = v;
      }
    }
    __syncthreads();
#pragma unroll
    for (int kt = 0; kt < 4; ++kt) {
      int kbyteA = kt * 64 + lk * 16;
      int kbyteB = ch * 256 + kbyteA;
      bf16x8 aF[2], bF[4];
#pragma unroll
      for (int mi = 0; mi < 2; ++mi) {
        int r = wv * 32 + mi * 16 + lr;
        aF[mi] = *reinterpret_cast<bf16x8*>((char*)As + r * 256 + (kbyteA ^ ((r & 7) << 4)));
      }
#pragma unroll
      for (int ni = 0; ni < 4; ++ni) {
        int c = ni * 16 + lr;
        bF[ni] = *reinterpret_cast<bf16x8*>((char*)Bs + c * 768 + (kbyteB ^ ((c & 7) << 4)));
      }
#pragma unroll
      for (int mi = 0; mi < 2; ++mi)
#pragma unroll
        for (int ni = 0; ni < 4; ++ni)
          acc[mi][ni] = __builtin_amdgcn_mfma_f32_16x16x32_bf16(aF[mi], bF[ni], acc[mi][ni], 0, 0, 0);
    }
  }

#pragma unroll
  for (int mi = 0; mi < 2; ++mi)
#pragma unroll
    for (int ni = 0; ni < 4; ++ni)
#pragma unroll
      for (int i = 0; i < 4; ++i) {
        int gr = row0 + wv * 32 + mi * 16 + lk * 4 + i;
        int gc = ni * 16 + lr;
        if (gr < n) C[(size_t)gr * 64 + gc] = f2bf(acc[mi][ni][i]);
      }
}

// ---------------- aggregation: out[r] = relu(dinv[r]*(self + sum dinv[s]*t[s]) + bias) ----------------
template <int F, int OUT_F32>
__global__ __launch_bounds__(256) void k_agg(const unsigned short* __restrict__ t, const int* __restrict__ rowptr,
                                             const int* __restrict__ col, const float* __restrict__ dinv,
                                             const float* __restrict__ bias, void* __restrict__ outp, int n) {
  const int G = F / 8;          // threads per row
  const int RPB = 256 / G;
  int g = threadIdx.x / G;
  int c = threadIdx.x % G;
  int r = blockIdx.x * RPB + g;
  if (r >= n) return;
  int f0 = c * 8;
  float di = dinv[r];
  float acc[8];
  {
    ushort8 sv = *reinterpret_cast<const ushort8*>(t + (size_t)r * F + f0);
#pragma unroll
    for (int j = 0; j < 8; ++j) acc[j] = di * bf2f(sv[j]);
  }
  int e1 = rowptr[r + 1];
  int e = rowptr[r];
  for (; e + 4 <= e1; e += 4) {
    int s0 = col[e], s1 = col[e + 1], s2 = col[e + 2], s3 = col[e + 3];
    float w0 = dinv[s0], w1 = dinv[s1], w2 = dinv[s2], w3 = dinv[s3];
    ushort8 u0 = *reinterpret_cast<const ushort8*>(t + (size_t)s0 * F + f0);
    ushort8 u1 = *reinterpret_cast<const ushort8*>(t + (size_t)s1 * F + f0);
    ushort8 u2 = *reinterpret_cast<const ushort8*>(t + (size_t)s2 * F + f0);
    ushort8 u3 = *reinterpret_cast<const ushort8*>(t + (size_t)s3 * F + f0);
#pragma unroll
    for (int j = 0; j < 8; ++j) {
      acc[j] += w0 * bf2f(u0[j]);
      acc[j] += w1 * bf2f(u1[j]);
      acc[j] += w2 * bf2f(u2[j]);
      acc[j] += w3 * bf2f(u3[j]);
    }
  }
  for (; e < e1; ++e) {
    int s = col[e];
    float w = dinv[s];
    ushort8 u = *reinterpret_cast<const ushort8*>(t + (size_t)s * F + f0);
#pragma unroll
    for (int j = 0; j < 8; ++j) acc[j] += w * bf2f(u[j]);
  }
  if (OUT_F32) {
    float* o = (float*)outp;
#pragma unroll
    for (int j = 0; j < 8; ++j) o[(size_t)r * F + f0 + j] = fmaxf(acc[j] * di + bias[f0 + j], 0.f);
  } else {
    ushort8 ov;
#pragma unroll
    for (int j = 0; j < 8; ++j) ov[j] = f2bf(fmaxf(acc[j] * di + bias[f0 + j], 0.f));
    *reinterpret_cast<ushort8*>((unsigned short*)outp + (size_t)r * F + f0) = ov;
  }
}

// ---------------- batchnorm ----------------
__global__ __launch_bounds__(256) void k_bnstats(const unsigned short* __restrict__ h, int n, float* __restrict__ sums) {
  __shared__ f32x4 red[256];
  int f2 = (threadIdx.x & 63) * 2;
  int rg = threadIdx.x >> 6;
  int r0 = blockIdx.x * 1024;
  int rend = min(r0 + 1024, n);
  float s0 = 0.f, s1 = 0.f, q0 = 0.f, q1 = 0.f;
  for (int r = r0 + rg; r < rend; r += 4) {
    unsigned int raw = *reinterpret_cast<const unsigned int*>(h + (size_t)r * 128 + f2);
    float a = bf2f((unsigned short)(raw & 0xffffu));
    float b = bf2f((unsigned short)(raw >> 16));
    s0 += a; s1 += b; q0 += a * a; q1 += b * b;
  }
  red[threadIdx.x] = (f32x4){s0, s1, q0, q1};
  __syncthreads();
  if (rg == 0) {
    f32x4 v = red[threadIdx.x];
    v += red[threadIdx.x + 64];
    v += red[threadIdx.x + 128];
    v += red[threadIdx.x + 192];
    atomicAdd(&sums[f2], v.x);
    atomicAdd(&sums[f2 + 1], v.y);
    atomicAdd(&sums[128 + f2], v.z);
    atomicAdd(&sums[128 + f2 + 1], v.w);
  }
}

__global__ void k_bnfinal(const float* __restrict__ sums, const float* __restrict__ gamma,
                          const float* __restrict__ beta, float* __restrict__ ss, float invN) {
  int f = threadIdx.x;
  float m = sums[f] * invN;
  float var = sums[128 + f] * invN - m * m;
  float sc = gamma[f] * rsqrtf(var + BN_EPS);
  ss[f] = sc;
  ss[128 + f] = beta[f] - m * sc;
}

__global__ __launch_bounds__(256) void k_bnapply(const unsigned short* __restrict__ a, unsigned short* __restrict__ o,
                                                 const float* __restrict__ ss, size_t nchunk) {
  for (size_t q = (size_t)blockIdx.x * 256 + threadIdx.x; q < nchunk; q += (size_t)gridDim.x * 256) {
    int f0 = (int)(q & 15) * 8;
    ushort8 v = *reinterpret_cast<const ushort8*>(a + q * 8);
    ushort8 rres;
#pragma unroll
    for (int j = 0; j < 8; ++j) rres[j] = f2bf(bf2f(v[j]) * ss[f0 + j] + ss[128 + f0 + j]);
    *reinterpret_cast<ushort8*>(o + q * 8) = rres;
  }
}

// ---------------- launch ----------------
extern "C" void kernel_launch(void* const* d_in, const int* in_sizes, int n_in,
                              void* d_out, int out_size, void* d_ws, size_t ws_size,
                              hipStream_t stream) {
  const float* x    = (const float*)d_in[0];
  const int*   ei   = (const int*)d_in[1];
  const float* W1   = (const float*)d_in[2];
  const float* b1   = (const float*)d_in[3];
  const float* W2   = (const float*)d_in[4];
  const float* b2   = (const float*)d_in[5];
  const float* Wout = (const float*)d_in[6];
  const float* bout = (const float*)d_in[7];
  const float* gamma= (const float*)d_in[8];
  const float* beta = (const float*)d_in[9];
  float* out = (float*)d_out;

  const int n = in_sizes[0] / 128;
  const int e = in_sizes[1] / 2;
  const int* src = ei;
  const int* dst = ei + e;

  char* ws = (char*)d_ws;
  size_t off = 0;
  auto alloc = [&](size_t bytes) -> void* {
    void* p = ws + off;
    off += (bytes + 255) & ~(size_t)255;
    return p;
  };
  int*   cnt    = (int*)alloc((size_t)n * 4);
  int*   cursor = (int*)alloc((size_t)n * 4);
  int*   rowptr = (int*)alloc(((size_t)n + 1) * 4);
  int*   bsum   = (int*)alloc(1024 * 4);
  float* dinv   = (float*)alloc((size_t)n * 4);
  float* sumsA  = (float*)alloc(256 * 4);
  float* sumsB  = (float*)alloc(256 * 4);
  float* ss1    = (float*)alloc(256 * 4);
  float* ss2    = (float*)alloc(256 * 4);
  int*   col    = (int*)alloc((size_t)e * 4);
  unsigned short* Wt1 = (unsigned short*)alloc(128 * 128 * 2);
  unsigned short* Wt2 = (unsigned short*)alloc(128 * 128 * 2);
  unsigned short* Wt3 = (unsigned short*)alloc(384 * 64 * 2);
  unsigned short* t    = (unsigned short*)alloc((size_t)n * 128 * 2);
  unsigned short* a    = (unsigned short*)alloc((size_t)n * 128 * 2);
  unsigned short* h1bn = (unsigned short*)alloc((size_t)n * 128 * 2);
  unsigned short* h2bn = (unsigned short*)alloc((size_t)n * 128 * 2);

  hipMemsetAsync(cnt, 0, (size_t)n * 4, stream);
  hipMemsetAsync(cursor, 0, (size_t)n * 4, stream);
  hipMemsetAsync(sumsA, 0, 512 * 4, stream);  // sumsA+sumsB contiguous

  int nbE = (e + 255) / 256;
  int nbN = (n + 255) / 256;
  k_count<<<nbE, 256, 0, stream>>>(dst, e, cnt);
  k_dinv<<<nbN, 256, 0, stream>>>(cnt, dinv, n);
  k_scan1<<<nbN, 256, 0, stream>>>(cnt, n, bsum);
  k_scan2<<<1, 1024, 0, stream>>>(bsum, nbN);
  k_scan3<<<nbN, 256, 0, stream>>>(cnt, n, bsum, rowptr, e);
  k_fill<<<nbE, 256, 0, stream>>>(src, dst, e, rowptr, cursor, col);
  k_cvtw<<<224, 256, 0, stream>>>(W1, W2, Wout, Wt1, Wt2, Wt3);

  int nbG = (n + 127) / 128;
  int nbA128 = (n + 15) / 16;
  int nbA64 = (n + 31) / 32;
  int nbS = (n + 1023) / 1024;
  float invN = 1.f / (float)n;

  // layer 1
  k_gemm128<1><<<nbG, 256, 0, stream>>>(x, Wt1, t, n);
  k_agg<128, 0><<<nbA128, 256, 0, stream>>>(t, rowptr, col, dinv, b1, a, n);
  k_bnstats<<<nbS, 256, 0, stream>>>(a, n, sumsA);
  k_bnfinal<<<1, 128, 0, stream>>>(sumsA, gamma, beta, ss1, invN);
  k_bnapply<<<2048, 256, 0, stream>>>(a, h1bn, ss1, (size_t)n * 16);

  // layer 2
  k_gemm128<0><<<nbG, 256, 0, stream>>>(h1bn, Wt2, t, n);
  k_agg<128, 0><<<nbA128, 256, 0, stream>>>(t, rowptr, col, dinv, b2, a, n);
  k_bnstats<<<nbS, 256, 0, stream>>>(a, n, sumsB);
  k_bnfinal<<<1, 128, 0, stream>>>(sumsB, gamma, beta, ss2, invN);
  k_bnapply<<<2048, 256, 0, stream>>>(a, h2bn, ss2, (size_t)n * 16);

  // layer 3
  k_gemm3<<<nbG, 256, 0, stream>>>(x, h1bn, h2bn, Wt3, t, n);
  k_agg<64, 1><<<nbA64, 256, 0, stream>>>(t, rowptr, col, dinv, bout, out, n);
}

// Round 3
// 307.228 us; speedup vs baseline: 3.3180x; 1.8515x over previous
//
#include <hip/hip_runtime.h>
#include <cstdint>
#include <cstddef>

#define BN_EPS 1e-5f
#define NBLK 256
#define EPBMAX 6400
#define BCAP 4096
#define NBANK 32

typedef __attribute__((ext_vector_type(8))) short  bf16x8;
typedef __attribute__((ext_vector_type(4))) float  f32x4;
typedef __attribute__((ext_vector_type(8))) unsigned short ushort8;

__device__ __forceinline__ float bf2f(unsigned short u) {
  union { unsigned int i; float f; } c; c.i = ((unsigned int)u) << 16; return c.f;
}
__device__ __forceinline__ unsigned short f2bf(float f) {
  union { float f; unsigned int i; } c; c.f = f;
  unsigned int u = c.i;
  return (unsigned short)((u + 0x7FFFu + ((u >> 16) & 1u)) >> 16);  // RNE
}

// ---------------- graph partition pipeline ----------------
// k_part: each of 256 blocks sorts its edge slice by bucket (dst>>7) in LDS,
// writes contiguous sorted sub-list (packed (d&127)<<25|src) + count/scan tables.
__global__ __launch_bounds__(256) void k_part(const int* __restrict__ src, const int* __restrict__ dst, int e, int epb,
                                              int* __restrict__ pairsG, int* __restrict__ cntT, int* __restrict__ scanT) {
  __shared__ int sbuf[EPBMAX];
  __shared__ int hist[1024];
  __shared__ int base[1024];
  __shared__ int tmp[256];
  int tid = threadIdx.x, b = blockIdx.x;
  int e0 = b * epb, e1 = min(e0 + epb, e);
  for (int i = tid; i < 1024; i += 256) hist[i] = 0;
  __syncthreads();
  for (int i = e0 + tid; i < e1; i += 256) atomicAdd(&hist[dst[i] >> 7], 1);
  __syncthreads();
  int c0 = hist[tid * 4], c1 = hist[tid * 4 + 1], c2 = hist[tid * 4 + 2], c3 = hist[tid * 4 + 3];
  int lsum = c0 + c1 + c2 + c3;
  tmp[tid] = lsum; __syncthreads();
  for (int off = 1; off < 256; off <<= 1) {
    int t = (tid >= off) ? tmp[tid - off] : 0; __syncthreads();
    tmp[tid] += t; __syncthreads();
  }
  int excl = tmp[tid] - lsum;
  base[tid * 4] = excl; base[tid * 4 + 1] = excl + c0;
  base[tid * 4 + 2] = excl + c0 + c1; base[tid * 4 + 3] = excl + c0 + c1 + c2;
  *(int4*)(cntT + b * 1024 + tid * 4) = make_int4(c0, c1, c2, c3);
  *(int4*)(scanT + b * 1024 + tid * 4) = make_int4(base[tid * 4], base[tid * 4 + 1], base[tid * 4 + 2], base[tid * 4 + 3]);
  __syncthreads();
  for (int i = e0 + tid; i < e1; i += 256) {
    int d = dst[i], s = src[i];
    int p = atomicAdd(&base[d >> 7], 1);
    sbuf[p] = ((d & 127) << 25) | s;
  }
  __syncthreads();
  int cnt = e1 - e0;
  for (int i = tid; i < cnt; i += 256) pairsG[e0 + i] = sbuf[i];
}

__global__ __launch_bounds__(256) void k_btot(const int* __restrict__ cntT, int* __restrict__ totals) {
  int k = blockIdx.x, tid = threadIdx.x;
  __shared__ int tmp[256];
  tmp[tid] = cntT[tid * 1024 + k];
  __syncthreads();
  for (int s = 128; s > 0; s >>= 1) {
    if (tid < s) tmp[tid] += tmp[tid + s];
    __syncthreads();
  }
  if (tid == 0) totals[k] = tmp[0];
}

__global__ __launch_bounds__(1024) void k_bscan(const int* __restrict__ totals, int* __restrict__ bbase, int nb, int e) {
  __shared__ int tmp[1024];
  int tid = threadIdx.x;
  int v = (tid < nb) ? totals[tid] : 0;
  tmp[tid] = v; __syncthreads();
  for (int off = 1; off < 1024; off <<= 1) {
    int t = (tid >= off) ? tmp[tid - off] : 0; __syncthreads();
    tmp[tid] += t; __syncthreads();
  }
  if (tid < nb) bbase[tid] = tmp[tid] - v;
  if (tid == 0) bbase[nb] = e;
}

// k_build: one block per bucket; gather sub-list segments, per-node CSR in LDS,
// coalesced col/rowptr/dinv writes.
__global__ __launch_bounds__(256) void k_build(const int* __restrict__ pairsG, const int* __restrict__ cntT,
                                               const int* __restrict__ scanT, const int* __restrict__ bbase_,
                                               int epb, int n, int nb,
                                               int* __restrict__ rowptr, int* __restrict__ colG, float* __restrict__ dinvG) {
  __shared__ int lpair[BCAP];
  __shared__ int lcol[BCAP];
  __shared__ int lcnt[128], lcur[128];
  __shared__ int tmp[256];
  int k = blockIdx.x, tid = threadIdx.x;
  int len = cntT[tid * 1024 + k];
  int sbase = tid * epb + scanT[tid * 1024 + k];
  tmp[tid] = len; __syncthreads();
  for (int off = 1; off < 256; off <<= 1) {
    int t = (tid >= off) ? tmp[tid - off] : 0; __syncthreads();
    tmp[tid] += t; __syncthreads();
  }
  int dpos = tmp[tid] - len;
  int cnt = tmp[255];
  for (int i = 0; i < len; ++i) lpair[dpos + i] = pairsG[sbase + i];
  if (tid < 128) lcnt[tid] = 0;
  __syncthreads();
  for (int j = tid; j < cnt; j += 256) atomicAdd(&lcnt[((unsigned)lpair[j]) >> 25], 1);
  __syncthreads();
  if (tid < 128) tmp[tid] = lcnt[tid];
  __syncthreads();
  for (int off = 1; off < 128; off <<= 1) {
    int t = (tid >= off && tid < 128) ? tmp[tid - off] : 0; __syncthreads();
    if (tid < 128) tmp[tid] += t;
    __syncthreads();
  }
  int bb = bbase_[k];
  if (tid < 128) {
    int excl = tmp[tid] - lcnt[tid];
    lcur[tid] = excl;
    int g = k * 128 + tid;
    if (g < n) {
      rowptr[g] = bb + excl;
      dinvG[g] = rsqrtf((float)lcnt[tid] + 1.0f);
    }
  }
  if (k == nb - 1 && tid == 0) rowptr[n] = bb + cnt;
  __syncthreads();
  for (int j = tid; j < cnt; j += 256) {
    int w = lpair[j];
    int p = atomicAdd(&lcur[((unsigned)w) >> 25], 1);
    lcol[p] = w & 0x01FFFFFF;
  }
  __syncthreads();
  for (int j = tid; j < cnt; j += 256) colG[bb + j] = lcol[j];
}

// ---------------- weight convert + transpose (f32 [K][N] -> bf16 [N][K]) ----------------
__global__ __launch_bounds__(256) void k_cvtw(const float* __restrict__ W1, const float* __restrict__ W2,
                                              const float* __restrict__ W3,
                                              unsigned short* __restrict__ Wt1, unsigned short* __restrict__ Wt2,
                                              unsigned short* __restrict__ Wt3) {
  int b = blockIdx.x, t = threadIdx.x;
  if (b < 64) {
    int idx = b * 256 + t; int k = idx >> 7, c = idx & 127;
    Wt1[c * 128 + k] = f2bf(W1[idx]);
  } else if (b < 128) {
    int idx = (b - 64) * 256 + t; int k = idx >> 7, c = idx & 127;
    Wt2[c * 128 + k] = f2bf(W2[idx]);
  } else {
    int idx = (b - 128) * 256 + t; int k = idx >> 6, c = idx & 63;   // [384][64]
    Wt3[c * 384 + k] = f2bf(W3[idx]);
  }
}

// ---------------- MFMA GEMM: C[n,128](bf16) = dinv[r] * (A[n,128] @ Wt^T), K=128 ----------------
// MODE 0: A = f32 raw (x). MODE 1: A = bf16 + per-feature affine ss (scale, shift).
template <int MODE>
__global__ __launch_bounds__(256) void k_gemm128(const void* __restrict__ Ap, const unsigned short* __restrict__ Bt,
                                                 const float* __restrict__ ss, const float* __restrict__ dinv,
                                                 unsigned short* __restrict__ C, int n) {
  __shared__ unsigned short As[128 * 128];
  __shared__ unsigned short Bs[128 * 128];
  __shared__ float ssl[256];
  const int tid = threadIdx.x;
  const int row0 = blockIdx.x * 128;
  if (MODE == 1 && tid < 256) ssl[tid] = ss[tid];

  {
    int colr = tid >> 1;
    int cbase = (tid & 1) * 8;
#pragma unroll
    for (int i = 0; i < 8; ++i) {
      int c16 = (cbase + i) * 16;
      int dstb = colr * 256 + (c16 ^ ((colr & 7) << 4));
      ushort8 v = *reinterpret_cast<const ushort8*>(Bt + colr * 128 + (c16 >> 1));
      *reinterpret_cast<ushort8*>((char*)Bs + dstb) = v;
    }
  }
  if (MODE == 1) __syncthreads();  // ssl ready before A staging uses it
  {
    int r = tid >> 1;
    int gr = row0 + r;
    int cbase = (tid & 1) * 8;
#pragma unroll
    for (int i = 0; i < 8; ++i) {
      int c16 = (cbase + i) * 16;
      int dstb = r * 256 + (c16 ^ ((r & 7) << 4));
      int f0 = c16 >> 1;
      ushort8 v = (ushort8)0;
      if (gr < n) {
        if (MODE == 0) {
          const float* A = (const float*)Ap;
          f32x4 v0 = *reinterpret_cast<const f32x4*>(A + (size_t)gr * 128 + f0);
          f32x4 v1 = *reinterpret_cast<const f32x4*>(A + (size_t)gr * 128 + f0 + 4);
#pragma unroll
          for (int j = 0; j < 4; ++j) { v[j] = f2bf(v0[j]); v[4 + j] = f2bf(v1[j]); }
        } else {
          const unsigned short* A = (const unsigned short*)Ap;
          ushort8 raw = *reinterpret_cast<const ushort8*>(A + (size_t)gr * 128 + f0);
#pragma unroll
          for (int j = 0; j < 8; ++j) v[j] = f2bf(bf2f(raw[j]) * ssl[f0 + j] + ssl[128 + f0 + j]);
        }
      }
      *reinterpret_cast<ushort8*>((char*)As + dstb) = v;
    }
  }
  __syncthreads();

  const int wv = tid >> 6;
  const int l = tid & 63;
  const int lr = l & 15;
  const int lk = l >> 4;

  f32x4 acc[2][8];
#pragma unroll
  for (int mi = 0; mi < 2; ++mi)
#pragma unroll
    for (int ni = 0; ni < 8; ++ni) acc[mi][ni] = (f32x4)0.f;

#pragma unroll
  for (int kt = 0; kt < 4; ++kt) {
    int kbyte = kt * 64 + lk * 16;
    bf16x8 aF[2], bF[8];
#pragma unroll
    for (int mi = 0; mi < 2; ++mi) {
      int r = wv * 32 + mi * 16 + lr;
      aF[mi] = *reinterpret_cast<bf16x8*>((char*)As + r * 256 + (kbyte ^ ((r & 7) << 4)));
    }
#pragma unroll
    for (int ni = 0; ni < 8; ++ni) {
      int c = ni * 16 + lr;
      bF[ni] = *reinterpret_cast<bf16x8*>((char*)Bs + c * 256 + (kbyte ^ ((c & 7) << 4)));
    }
#pragma unroll
    for (int mi = 0; mi < 2; ++mi)
#pragma unroll
      for (int ni = 0; ni < 8; ++ni)
        acc[mi][ni] = __builtin_amdgcn_mfma_f32_16x16x32_bf16(aF[mi], bF[ni], acc[mi][ni], 0, 0, 0);
  }

#pragma unroll
  for (int mi = 0; mi < 2; ++mi) {
#pragma unroll
    for (int i = 0; i < 4; ++i) {
      int gr = row0 + wv * 32 + mi * 16 + lk * 4 + i;
      if (gr < n) {
        float di = dinv[gr];
#pragma unroll
        for (int ni = 0; ni < 8; ++ni) {
          int gc = ni * 16 + lr;
          C[(size_t)gr * 128 + gc] = f2bf(acc[mi][ni][i] * di);
        }
      }
    }
  }
}

// ---------------- MFMA GEMM3: C[n,64](bf16) = dinv * ([x | bn(a1) | bn(a2)] @ Wt3^T), K=384 ----------------
__global__ __launch_bounds__(256) void k_gemm3(const float* __restrict__ x, const unsigned short* __restrict__ a1,
                                               const unsigned short* __restrict__ a2,
                                               const float* __restrict__ ss1, const float* __restrict__ ss2,
                                               const unsigned short* __restrict__ Bt3, const float* __restrict__ dinv,
                                               unsigned short* __restrict__ C, int n) {
  __shared__ unsigned short As[128 * 128];
  __shared__ unsigned short Bs[64 * 384];
  __shared__ float ssl[512];
  const int tid = threadIdx.x;
  const int row0 = blockIdx.x * 128;
  if (tid < 256) { ssl[tid] = ss1[tid]; ssl[256 + tid] = ss2[tid]; }

  {
    int colr = tid >> 2;
    int cb = tid & 3;
#pragma unroll
    for (int i = 0; i < 12; ++i) {
      int c16 = (cb + 4 * i) * 16;
      int dstb = colr * 768 + (c16 ^ ((colr & 7) << 4));
      ushort8 v = *reinterpret_cast<const ushort8*>(Bt3 + colr * 384 + (c16 >> 1));
      *reinterpret_cast<ushort8*>((char*)Bs + dstb) = v;
    }
  }

  const int wv = tid >> 6;
  const int l = tid & 63;
  const int lr = l & 15;
  const int lk = l >> 4;

  f32x4 acc[2][4];
#pragma unroll
  for (int mi = 0; mi < 2; ++mi)
#pragma unroll
    for (int ni = 0; ni < 4; ++ni) acc[mi][ni] = (f32x4)0.f;

  for (int ch = 0; ch < 3; ++ch) {
    __syncthreads();
    {
      int r = tid >> 1;
      int gr = row0 + r;
      int cbase = (tid & 1) * 8;
#pragma unroll
      for (int i = 0; i < 8; ++i) {
        int c16 = (cbase + i) * 16;
        int dstb = r * 256 + (c16 ^ ((r & 7) << 4));
        int f0 = c16 >> 1;
        ushort8 v = (ushort8)0;
        if (gr < n) {
          if (ch == 0) {
            f32x4 v0 = *reinterpret_cast<const f32x4*>(x + (size_t)gr * 128 + f0);
            f32x4 v1 = *reinterpret_cast<const f32x4*>(x + (size_t)gr * 128 + f0 + 4);
#pragma unroll
            for (int j = 0; j < 4; ++j) { v[j] = f2bf(v0[j]); v[4 + j] = f2bf(v1[j]); }
          } else {
            const unsigned short* A = (ch == 1) ? a1 : a2;
            const float* sl = ssl + (ch - 1) * 256;
            ushort8 raw = *reinterpret_cast<const ushort8*>(A + (size_t)gr * 128 + f0);
#pragma unroll
            for (int j = 0; j < 8; ++j) v[j] = f2bf(bf2f(raw[j]) * sl[f0 + j] + sl[128 + f0 + j]);
          }
        }
        *reinterpret_cast<ushort8*>((char*)As + dstb) = v;
      }
    }
    __syncthreads();
#pragma unroll
    for (int kt = 0; kt < 4; ++kt) {
      int kbyteA = kt * 64 + lk * 16;
      int kbyteB = ch * 256 + kbyteA;
      bf16x8 aF[2], bF[4];
#pragma unroll
      for (int mi = 0; mi < 2; ++mi) {
        int r = wv * 32 + mi * 16 + lr;
        aF[mi] = *reinterpret_cast<bf16x8*>((char*)As + r * 256 + (kbyteA ^ ((r & 7) << 4)));
      }
#pragma unroll
      for (int ni = 0; ni < 4; ++ni) {
        int c = ni * 16 + lr;
        bF[ni] = *reinterpret_cast<bf16x8*>((char*)Bs + c * 768 + (kbyteB ^ ((c & 7) << 4)));
      }
#pragma unroll
      for (int mi = 0; mi < 2; ++mi)
#pragma unroll
        for (int ni = 0; ni < 4; ++ni)
          acc[mi][ni] = __builtin_amdgcn_mfma_f32_16x16x32_bf16(aF[mi], bF[ni], acc[mi][ni], 0, 0, 0);
    }
  }

#pragma unroll
  for (int mi = 0; mi < 2; ++mi) {
#pragma unroll
    for (int i = 0; i < 4; ++i) {
      int gr = row0 + wv * 32 + mi * 16 + lk * 4 + i;
      if (gr < n) {
        float di = dinv[gr];
#pragma unroll
        for (int ni = 0; ni < 4; ++ni) {
          int gc = ni * 16 + lr;
          C[(size_t)gr * 64 + gc] = f2bf(acc[mi][ni][i] * di);
        }
      }
    }
  }
}

// ---------------- aggregation: out[r] = relu(dinv[r]*(t'[r] + sum t'[s]) + bias), t' prescaled ----------------
// STATS: also accumulate per-feature sum/sumsq into bank[blockIdx&31][256].
template <int F, int STATS, int OUT_F32>
__global__ __launch_bounds__(256) void k_agg(const unsigned short* __restrict__ t, const int* __restrict__ rowptr,
                                             const int* __restrict__ col, const float* __restrict__ dinv,
                                             const float* __restrict__ bias, void* __restrict__ outp,
                                             float* __restrict__ bank, int n) {
  const int G = F / 8;          // threads per row
  const int RPB = 256 / G;
  int g = threadIdx.x / G;
  int c = threadIdx.x % G;
  int r = blockIdx.x * RPB + g;
  bool act = (r < n);
  float v[8];
#pragma unroll
  for (int j = 0; j < 8; ++j) v[j] = 0.f;
  int f0 = c * 8;
  if (act) {
    float di = dinv[r];
    float acc[8];
    {
      ushort8 sv = *reinterpret_cast<const ushort8*>(t + (size_t)r * F + f0);
#pragma unroll
      for (int j = 0; j < 8; ++j) acc[j] = bf2f(sv[j]);   // self term (prescaled)
    }
    int e1 = rowptr[r + 1];
    int e = rowptr[r];
    for (; e + 4 <= e1; e += 4) {
      int s0 = col[e], s1 = col[e + 1], s2 = col[e + 2], s3 = col[e + 3];
      ushort8 u0 = *reinterpret_cast<const ushort8*>(t + (size_t)s0 * F + f0);
      ushort8 u1 = *reinterpret_cast<const ushort8*>(t + (size_t)s1 * F + f0);
      ushort8 u2 = *reinterpret_cast<const ushort8*>(t + (size_t)s2 * F + f0);
      ushort8 u3 = *reinterpret_cast<const ushort8*>(t + (size_t)s3 * F + f0);
#pragma unroll
      for (int j = 0; j < 8; ++j)
        acc[j] += bf2f(u0[j]) + bf2f(u1[j]) + bf2f(u2[j]) + bf2f(u3[j]);
    }
    for (; e < e1; ++e) {
      int s = col[e];
      ushort8 u = *reinterpret_cast<const ushort8*>(t + (size_t)s * F + f0);
#pragma unroll
      for (int j = 0; j < 8; ++j) acc[j] += bf2f(u[j]);
    }
#pragma unroll
    for (int j = 0; j < 8; ++j) v[j] = fmaxf(acc[j] * di + bias[f0 + j], 0.f);
    if (OUT_F32) {
      float* o = (float*)outp;
#pragma unroll
      for (int j = 0; j < 8; ++j) o[(size_t)r * F + f0 + j] = v[j];
    } else {
      ushort8 ov;
#pragma unroll
      for (int j = 0; j < 8; ++j) ov[j] = f2bf(v[j]);
      *reinterpret_cast<ushort8*>((unsigned short*)outp + (size_t)r * F + f0) = ov;
    }
  }
  if (STATS) {
    __shared__ float sA[256 * 8];
    __shared__ float sB[256 * 8];
#pragma unroll
    for (int j = 0; j < 8; ++j) { sA[threadIdx.x * 8 + j] = v[j]; sB[threadIdx.x * 8 + j] = v[j] * v[j]; }
    __syncthreads();
    if (threadIdx.x < 128) {
      int f = threadIdx.x;
      int cc = f >> 3, jj = f & 7;
      float s = 0.f, q = 0.f;
#pragma unroll
      for (int gg = 0; gg < 16; ++gg) {
        s += sA[(gg * 16 + cc) * 8 + jj];
        q += sB[(gg * 16 + cc) * 8 + jj];
      }
      float* bk = bank + (blockIdx.x & (NBANK - 1)) * 256;
      atomicAdd(&bk[f], s);
      atomicAdd(&bk[128 + f], q);
    }
  }
}

// ---------------- batchnorm finalize: reduce banks -> scale/shift ----------------
__global__ void k_bnfinal(const float* __restrict__ bank, const float* __restrict__ gamma,
                          const float* __restrict__ beta, float* __restrict__ ss, float invN) {
  int f = threadIdx.x;   // 128 threads
  float s = 0.f, q = 0.f;
  for (int b = 0; b < NBANK; ++b) { s += bank[b * 256 + f]; q += bank[b * 256 + 128 + f]; }
  float m = s * invN;
  float var = q * invN - m * m;
  float sc = gamma[f] * rsqrtf(var + BN_EPS);
  ss[f] = sc;
  ss[128 + f] = beta[f] - m * sc;
}

// ---------------- launch ----------------
extern "C" void kernel_launch(void* const* d_in, const int* in_sizes, int n_in,
                              void* d_out, int out_size, void* d_ws, size_t ws_size,
                              hipStream_t stream) {
  const float* x    = (const float*)d_in[0];
  const int*   ei   = (const int*)d_in[1];
  const float* W1   = (const float*)d_in[2];
  const float* b1   = (const float*)d_in[3];
  const float* W2   = (const float*)d_in[4];
  const float* b2   = (const float*)d_in[5];
  const float* Wout = (const float*)d_in[6];
  const float* bout = (const float*)d_in[7];
  const float* gamma= (const float*)d_in[8];
  const float* beta = (const float*)d_in[9];
  float* out = (float*)d_out;

  const int n = in_sizes[0] / 128;
  const int e = in_sizes[1] / 2;
  const int* src = ei;
  const int* dst = ei + e;
  const int nb = (n + 127) >> 7;          // buckets of 128 nodes
  const int epb = (e + NBLK - 1) / NBLK;  // edges per partition block

  char* ws = (char*)d_ws;
  size_t off = 0;
  auto alloc = [&](size_t bytes) -> void* {
    void* p = ws + off;
    off += (bytes + 255) & ~(size_t)255;
    return p;
  };
  int*   pairsG = (int*)alloc((size_t)NBLK * epb * 4);
  int*   cntT   = (int*)alloc((size_t)NBLK * 1024 * 4);
  int*   scanT  = (int*)alloc((size_t)NBLK * 1024 * 4);
  int*   totals = (int*)alloc(1024 * 4);
  int*   bbase  = (int*)alloc(1025 * 4);
  int*   rowptr = (int*)alloc(((size_t)n + 1) * 4);
  float* dinv   = (float*)alloc((size_t)n * 4);
  int*   col    = (int*)alloc((size_t)e * 4);
  float* bank1  = (float*)alloc(NBANK * 256 * 4);
  float* bank2  = (float*)alloc(NBANK * 256 * 4);
  float* ss1    = (float*)alloc(256 * 4);
  float* ss2    = (float*)alloc(256 * 4);
  unsigned short* Wt1 = (unsigned short*)alloc(128 * 128 * 2);
  unsigned short* Wt2 = (unsigned short*)alloc(128 * 128 * 2);
  unsigned short* Wt3 = (unsigned short*)alloc(384 * 64 * 2);
  unsigned short* t   = (unsigned short*)alloc((size_t)n * 128 * 2);
  unsigned short* a1  = (unsigned short*)alloc((size_t)n * 128 * 2);
  unsigned short* a2  = (unsigned short*)alloc((size_t)n * 128 * 2);

  hipMemsetAsync(bank1, 0, (size_t)NBANK * 256 * 4 * 2, stream);  // bank1+bank2 contiguous

  // graph build
  k_part<<<NBLK, 256, 0, stream>>>(src, dst, e, epb, pairsG, cntT, scanT);
  k_btot<<<nb, 256, 0, stream>>>(cntT, totals);
  k_bscan<<<1, 1024, 0, stream>>>(totals, bbase, nb, e);
  k_build<<<nb, 256, 0, stream>>>(pairsG, cntT, scanT, bbase, epb, n, nb, rowptr, col, dinv);
  k_cvtw<<<224, 256, 0, stream>>>(W1, W2, Wout, Wt1, Wt2, Wt3);

  int nbG = (n + 127) / 128;
  int nbA128 = (n + 15) / 16;
  int nbA64 = (n + 31) / 32;
  float invN = 1.f / (float)n;

  // layer 1
  k_gemm128<0><<<nbG, 256, 0, stream>>>(x, Wt1, nullptr, dinv, t, n);
  k_agg<128, 1, 0><<<nbA128, 256, 0, stream>>>(t, rowptr, col, dinv, b1, a1, bank1, n);
  k_bnfinal<<<1, 128, 0, stream>>>(bank1, gamma, beta, ss1, invN);

  // layer 2
  k_gemm128<1><<<nbG, 256, 0, stream>>>(a1, Wt2, ss1, dinv, t, n);
  k_agg<128, 1, 0><<<nbA128, 256, 0, stream>>>(t, rowptr, col, dinv, b2, a2, bank2, n);
  k_bnfinal<<<1, 128, 0, stream>>>(bank2, gamma, beta, ss2, invN);

  // layer 3
  k_gemm3<<<nbG, 256, 0, stream>>>(x, a1, a2, ss1, ss2, Wt3, dinv, t, n);
  k_agg<64, 0, 1><<<nbA64, 256, 0, stream>>>(t, rowptr, col, dinv, bout, out, nullptr, n);
}

// Round 4
// 302.888 us; speedup vs baseline: 3.3655x; 1.0143x over previous
//
#include <hip/hip_runtime.h>
#include <cstdint>
#include <cstddef>

#define BN_EPS 1e-5f
#define NBLK 256
#define EPBMAX 6400
#define BCAP 4096
#define NBANK 32

typedef __attribute__((ext_vector_type(8))) short  bf16x8;
typedef __attribute__((ext_vector_type(4))) float  f32x4;
typedef __attribute__((ext_vector_type(8))) unsigned short ushort8;

__device__ __forceinline__ float bf2f(unsigned short u) {
  union { unsigned int i; float f; } c; c.i = ((unsigned int)u) << 16; return c.f;
}
__device__ __forceinline__ unsigned short f2bf(float f) {
  union { float f; unsigned int i; } c; c.f = f;
  unsigned int u = c.i;
  return (unsigned short)((u + 0x7FFFu + ((u >> 16) & 1u)) >> 16);  // RNE
}

// ---------------- graph partition pipeline ----------------
__global__ __launch_bounds__(256) void k_part(const int* __restrict__ src, const int* __restrict__ dst, int e, int epb,
                                              int* __restrict__ pairsG, int* __restrict__ cntT, int* __restrict__ scanT) {
  __shared__ int sbuf[EPBMAX];
  __shared__ int hist[1024];
  __shared__ int base[1024];
  __shared__ int tmp[256];
  int tid = threadIdx.x, b = blockIdx.x;
  int e0 = b * epb, e1 = min(e0 + epb, e);
  for (int i = tid; i < 1024; i += 256) hist[i] = 0;
  __syncthreads();
  for (int i = e0 + tid; i < e1; i += 256) atomicAdd(&hist[dst[i] >> 7], 1);
  __syncthreads();
  int c0 = hist[tid * 4], c1 = hist[tid * 4 + 1], c2 = hist[tid * 4 + 2], c3 = hist[tid * 4 + 3];
  int lsum = c0 + c1 + c2 + c3;
  tmp[tid] = lsum; __syncthreads();
  for (int off = 1; off < 256; off <<= 1) {
    int t = (tid >= off) ? tmp[tid - off] : 0; __syncthreads();
    tmp[tid] += t; __syncthreads();
  }
  int excl = tmp[tid] - lsum;
  base[tid * 4] = excl; base[tid * 4 + 1] = excl + c0;
  base[tid * 4 + 2] = excl + c0 + c1; base[tid * 4 + 3] = excl + c0 + c1 + c2;
  *(int4*)(cntT + b * 1024 + tid * 4) = make_int4(c0, c1, c2, c3);
  *(int4*)(scanT + b * 1024 + tid * 4) = make_int4(base[tid * 4], base[tid * 4 + 1], base[tid * 4 + 2], base[tid * 4 + 3]);
  __syncthreads();
  for (int i = e0 + tid; i < e1; i += 256) {
    int d = dst[i], s = src[i];
    int p = atomicAdd(&base[d >> 7], 1);
    sbuf[p] = ((d & 127) << 25) | s;
  }
  __syncthreads();
  int cnt = e1 - e0;
  for (int i = tid; i < cnt; i += 256) pairsG[e0 + i] = sbuf[i];
}

__global__ __launch_bounds__(256) void k_btot(const int* __restrict__ cntT, int* __restrict__ totals) {
  int k = blockIdx.x, tid = threadIdx.x;
  __shared__ int tmp[256];
  tmp[tid] = cntT[tid * 1024 + k];
  __syncthreads();
  for (int s = 128; s > 0; s >>= 1) {
    if (tid < s) tmp[tid] += tmp[tid + s];
    __syncthreads();
  }
  if (tid == 0) totals[k] = tmp[0];
}

__global__ __launch_bounds__(1024) void k_bscan(const int* __restrict__ totals, int* __restrict__ bbase, int nb, int e) {
  __shared__ int tmp[1024];
  int tid = threadIdx.x;
  int v = (tid < nb) ? totals[tid] : 0;
  tmp[tid] = v; __syncthreads();
  for (int off = 1; off < 1024; off <<= 1) {
    int t = (tid >= off) ? tmp[tid - off] : 0; __syncthreads();
    tmp[tid] += t; __syncthreads();
  }
  if (tid < nb) bbase[tid] = tmp[tid] - v;
  if (tid == 0) bbase[nb] = e;
}

__global__ __launch_bounds__(256) void k_build(const int* __restrict__ pairsG, const int* __restrict__ cntT,
                                               const int* __restrict__ scanT, const int* __restrict__ bbase_,
                                               int epb, int n, int nb,
                                               int* __restrict__ rowptr, int* __restrict__ colG, float* __restrict__ dinvG) {
  __shared__ int lpair[BCAP];
  __shared__ int lcol[BCAP];
  __shared__ int lcnt[128], lcur[128];
  __shared__ int tmp[256];
  int k = blockIdx.x, tid = threadIdx.x;
  int len = cntT[tid * 1024 + k];
  int sbase = tid * epb + scanT[tid * 1024 + k];
  tmp[tid] = len; __syncthreads();
  for (int off = 1; off < 256; off <<= 1) {
    int t = (tid >= off) ? tmp[tid - off] : 0; __syncthreads();
    tmp[tid] += t; __syncthreads();
  }
  int dpos = tmp[tid] - len;
  int cnt = tmp[255];
  for (int i = 0; i < len; ++i) lpair[dpos + i] = pairsG[sbase + i];
  if (tid < 128) lcnt[tid] = 0;
  __syncthreads();
  for (int j = tid; j < cnt; j += 256) atomicAdd(&lcnt[((unsigned)lpair[j]) >> 25], 1);
  __syncthreads();
  if (tid < 128) tmp[tid] = lcnt[tid];
  __syncthreads();
  for (int off = 1; off < 128; off <<= 1) {
    int t = (tid >= off && tid < 128) ? tmp[tid - off] : 0; __syncthreads();
    if (tid < 128) tmp[tid] += t;
    __syncthreads();
  }
  int bb = bbase_[k];
  if (tid < 128) {
    int excl = tmp[tid] - lcnt[tid];
    lcur[tid] = excl;
    int g = k * 128 + tid;
    if (g < n) {
      rowptr[g] = bb + excl;
      dinvG[g] = rsqrtf((float)lcnt[tid] + 1.0f);
    }
  }
  if (k == nb - 1 && tid == 0) rowptr[n] = bb + cnt;
  __syncthreads();
  for (int j = tid; j < cnt; j += 256) {
    int w = lpair[j];
    int p = atomicAdd(&lcur[((unsigned)w) >> 25], 1);
    lcol[p] = w & 0x01FFFFFF;
  }
  __syncthreads();
  for (int j = tid; j < cnt; j += 256) colG[bb + j] = lcol[j];
}

// ---------------- weight convert + transpose (f32 [K][N] -> bf16 [N][K]) ----------------
__global__ __launch_bounds__(256) void k_cvtw(const float* __restrict__ W1, const float* __restrict__ W2,
                                              const float* __restrict__ W3,
                                              unsigned short* __restrict__ Wt1, unsigned short* __restrict__ Wt2,
                                              unsigned short* __restrict__ Wt3) {
  int b = blockIdx.x, t = threadIdx.x;
  if (b < 64) {
    int idx = b * 256 + t; int k = idx >> 7, c = idx & 127;
    Wt1[c * 128 + k] = f2bf(W1[idx]);
  } else if (b < 128) {
    int idx = (b - 64) * 256 + t; int k = idx >> 7, c = idx & 127;
    Wt2[c * 128 + k] = f2bf(W2[idx]);
  } else {
    int idx = (b - 128) * 256 + t; int k = idx >> 6, c = idx & 63;   // [384][64]
    Wt3[c * 384 + k] = f2bf(W3[idx]);
  }
}

// ---------------- MFMA GEMM: C[n,128](bf16) = dinv[r] * (A[n,128] @ Wt^T), K=128 ----------------
template <int MODE>
__global__ __launch_bounds__(256) void k_gemm128(const void* __restrict__ Ap, const unsigned short* __restrict__ Bt,
                                                 const float* __restrict__ ss, const float* __restrict__ dinv,
                                                 unsigned short* __restrict__ C, int n) {
  __shared__ unsigned short As[128 * 128];
  __shared__ unsigned short Bs[128 * 128];
  __shared__ float ssl[256];
  const int tid = threadIdx.x;
  const int row0 = blockIdx.x * 128;
  if (MODE == 1 && tid < 256) ssl[tid] = ss[tid];

  {
    int colr = tid >> 1;
    int cbase = (tid & 1) * 8;
#pragma unroll
    for (int i = 0; i < 8; ++i) {
      int c16 = (cbase + i) * 16;
      int dstb = colr * 256 + (c16 ^ ((colr & 7) << 4));
      ushort8 v = *reinterpret_cast<const ushort8*>(Bt + colr * 128 + (c16 >> 1));
      *reinterpret_cast<ushort8*>((char*)Bs + dstb) = v;
    }
  }
  if (MODE == 1) __syncthreads();
  {
    int r = tid >> 1;
    int gr = row0 + r;
    int cbase = (tid & 1) * 8;
#pragma unroll
    for (int i = 0; i < 8; ++i) {
      int c16 = (cbase + i) * 16;
      int dstb = r * 256 + (c16 ^ ((r & 7) << 4));
      int f0 = c16 >> 1;
      ushort8 v = (ushort8)0;
      if (gr < n) {
        if (MODE == 0) {
          const float* A = (const float*)Ap;
          f32x4 v0 = *reinterpret_cast<const f32x4*>(A + (size_t)gr * 128 + f0);
          f32x4 v1 = *reinterpret_cast<const f32x4*>(A + (size_t)gr * 128 + f0 + 4);
#pragma unroll
          for (int j = 0; j < 4; ++j) { v[j] = f2bf(v0[j]); v[4 + j] = f2bf(v1[j]); }
        } else {
          const unsigned short* A = (const unsigned short*)Ap;
          ushort8 raw = *reinterpret_cast<const ushort8*>(A + (size_t)gr * 128 + f0);
#pragma unroll
          for (int j = 0; j < 8; ++j) v[j] = f2bf(bf2f(raw[j]) * ssl[f0 + j] + ssl[128 + f0 + j]);
        }
      }
      *reinterpret_cast<ushort8*>((char*)As + dstb) = v;
    }
  }
  __syncthreads();

  const int wv = tid >> 6;
  const int l = tid & 63;
  const int lr = l & 15;
  const int lk = l >> 4;

  f32x4 acc[2][8];
#pragma unroll
  for (int mi = 0; mi < 2; ++mi)
#pragma unroll
    for (int ni = 0; ni < 8; ++ni) acc[mi][ni] = (f32x4)0.f;

#pragma unroll
  for (int kt = 0; kt < 4; ++kt) {
    int kbyte = kt * 64 + lk * 16;
    bf16x8 aF[2], bF[8];
#pragma unroll
    for (int mi = 0; mi < 2; ++mi) {
      int r = wv * 32 + mi * 16 + lr;
      aF[mi] = *reinterpret_cast<bf16x8*>((char*)As + r * 256 + (kbyte ^ ((r & 7) << 4)));
    }
#pragma unroll
    for (int ni = 0; ni < 8; ++ni) {
      int c = ni * 16 + lr;
      bF[ni] = *reinterpret_cast<bf16x8*>((char*)Bs + c * 256 + (kbyte ^ ((c & 7) << 4)));
    }
#pragma unroll
    for (int mi = 0; mi < 2; ++mi)
#pragma unroll
      for (int ni = 0; ni < 8; ++ni)
        acc[mi][ni] = __builtin_amdgcn_mfma_f32_16x16x32_bf16(aF[mi], bF[ni], acc[mi][ni], 0, 0, 0);
  }

#pragma unroll
  for (int mi = 0; mi < 2; ++mi) {
#pragma unroll
    for (int i = 0; i < 4; ++i) {
      int gr = row0 + wv * 32 + mi * 16 + lk * 4 + i;
      if (gr < n) {
        float di = dinv[gr];
#pragma unroll
        for (int ni = 0; ni < 8; ++ni) {
          int gc = ni * 16 + lr;
          C[(size_t)gr * 128 + gc] = f2bf(acc[mi][ni][i] * di);
        }
      }
    }
  }
}

// ---------------- MFMA GEMM3 ----------------
__global__ __launch_bounds__(256) void k_gemm3(const float* __restrict__ x, const unsigned short* __restrict__ a1,
                                               const unsigned short* __restrict__ a2,
                                               const float* __restrict__ ss1, const float* __restrict__ ss2,
                                               const unsigned short* __restrict__ Bt3, const float* __restrict__ dinv,
                                               unsigned short* __restrict__ C, int n) {
  __shared__ unsigned short As[128 * 128];
  __shared__ unsigned short Bs[64 * 384];
  __shared__ float ssl[512];
  const int tid = threadIdx.x;
  const int row0 = blockIdx.x * 128;
  if (tid < 256) { ssl[tid] = ss1[tid]; ssl[256 + tid] = ss2[tid]; }

  {
    int colr = tid >> 2;
    int cb = tid & 3;
#pragma unroll
    for (int i = 0; i < 12; ++i) {
      int c16 = (cb + 4 * i) * 16;
      int dstb = colr * 768 + (c16 ^ ((colr & 7) << 4));
      ushort8 v = *reinterpret_cast<const ushort8*>(Bt3 + colr * 384 + (c16 >> 1));
      *reinterpret_cast<ushort8*>((char*)Bs + dstb) = v;
    }
  }

  const int wv = tid >> 6;
  const int l = tid & 63;
  const int lr = l & 15;
  const int lk = l >> 4;

  f32x4 acc[2][4];
#pragma unroll
  for (int mi = 0; mi < 2; ++mi)
#pragma unroll
    for (int ni = 0; ni < 4; ++ni) acc[mi][ni] = (f32x4)0.f;

  for (int ch = 0; ch < 3; ++ch) {
    __syncthreads();
    {
      int r = tid >> 1;
      int gr = row0 + r;
      int cbase = (tid & 1) * 8;
#pragma unroll
      for (int i = 0; i < 8; ++i) {
        int c16 = (cbase + i) * 16;
        int dstb = r * 256 + (c16 ^ ((r & 7) << 4));
        int f0 = c16 >> 1;
        ushort8 v = (ushort8)0;
        if (gr < n) {
          if (ch == 0) {
            f32x4 v0 = *reinterpret_cast<const f32x4*>(x + (size_t)gr * 128 + f0);
            f32x4 v1 = *reinterpret_cast<const f32x4*>(x + (size_t)gr * 128 + f0 + 4);
#pragma unroll
            for (int j = 0; j < 4; ++j) { v[j] = f2bf(v0[j]); v[4 + j] = f2bf(v1[j]); }
          } else {
            const unsigned short* A = (ch == 1) ? a1 : a2;
            const float* sl = ssl + (ch - 1) * 256;
            ushort8 raw = *reinterpret_cast<const ushort8*>(A + (size_t)gr * 128 + f0);
#pragma unroll
            for (int j = 0; j < 8; ++j) v[j] = f2bf(bf2f(raw[j]) * sl[f0 + j] + sl[128 + f0 + j]);
          }
        }
        *reinterpret_cast<ushort8*>((char*)As + dstb) = v;
      }
    }
    __syncthreads();
#pragma unroll
    for (int kt = 0; kt < 4; ++kt) {
      int kbyteA = kt * 64 + lk * 16;
      int kbyteB = ch * 256 + kbyteA;
      bf16x8 aF[2], bF[4];
#pragma unroll
      for (int mi = 0; mi < 2; ++mi) {
        int r = wv * 32 + mi * 16 + lr;
        aF[mi] = *reinterpret_cast<bf16x8*>((char*)As + r * 256 + (kbyteA ^ ((r & 7) << 4)));
      }
#pragma unroll
      for (int ni = 0; ni < 4; ++ni) {
        int c = ni * 16 + lr;
        bF[ni] = *reinterpret_cast<bf16x8*>((char*)Bs + c * 768 + (kbyteB ^ ((c & 7) << 4)));
      }
#pragma unroll
      for (int mi = 0; mi < 2; ++mi)
#pragma unroll
        for (int ni = 0; ni < 4; ++ni)
          acc[mi][ni] = __builtin_amdgcn_mfma_f32_16x16x32_bf16(aF[mi], bF[ni], acc[mi][ni], 0, 0, 0);
    }
  }

#pragma unroll
  for (int mi = 0; mi < 2; ++mi) {
#pragma unroll
    for (int i = 0; i < 4; ++i) {
      int gr = row0 + wv * 32 + mi * 16 + lk * 4 + i;
      if (gr < n) {
        float di = dinv[gr];
#pragma unroll
        for (int ni = 0; ni < 4; ++ni) {
          int gc = ni * 16 + lr;
          C[(size_t)gr * 64 + gc] = f2bf(acc[mi][ni][i] * di);
        }
      }
    }
  }
}

// ---------------- aggregation with deep gather pipeline ----------------
template <int F, int STATS, int OUT_F32>
__global__ __launch_bounds__(256) void k_agg(const unsigned short* __restrict__ t, const int* __restrict__ rowptr,
                                             const int* __restrict__ col, const float* __restrict__ dinv,
                                             const float* __restrict__ bias, void* __restrict__ outp,
                                             float* __restrict__ bank, int n) {
  const int G = F / 8;          // threads per row
  const int RPB = 256 / G;
  int g = threadIdx.x / G;
  int c = threadIdx.x % G;
  int r = blockIdx.x * RPB + g;
  bool act = (r < n);
  float v[8];
#pragma unroll
  for (int j = 0; j < 8; ++j) v[j] = 0.f;
  int f0 = c * 8;
  if (act) {
    float di = dinv[r];
    int e = rowptr[r];
    int e1 = rowptr[r + 1];
    float acc[8];
    {
      ushort8 sv = *reinterpret_cast<const ushort8*>(t + (size_t)r * F + f0);
#pragma unroll
      for (int j = 0; j < 8; ++j) acc[j] = bf2f(sv[j]);   // self term (prescaled)
    }
    // 8-deep gather pipeline: 8 independent col loads -> 8 independent 16B gathers
    for (; e + 8 <= e1; e += 8) {
      int s0 = col[e],     s1 = col[e + 1], s2 = col[e + 2], s3 = col[e + 3];
      int s4 = col[e + 4], s5 = col[e + 5], s6 = col[e + 6], s7 = col[e + 7];
      ushort8 u0 = *reinterpret_cast<const ushort8*>(t + (size_t)s0 * F + f0);
      ushort8 u1 = *reinterpret_cast<const ushort8*>(t + (size_t)s1 * F + f0);
      ushort8 u2 = *reinterpret_cast<const ushort8*>(t + (size_t)s2 * F + f0);
      ushort8 u3 = *reinterpret_cast<const ushort8*>(t + (size_t)s3 * F + f0);
      ushort8 u4 = *reinterpret_cast<const ushort8*>(t + (size_t)s4 * F + f0);
      ushort8 u5 = *reinterpret_cast<const ushort8*>(t + (size_t)s5 * F + f0);
      ushort8 u6 = *reinterpret_cast<const ushort8*>(t + (size_t)s6 * F + f0);
      ushort8 u7 = *reinterpret_cast<const ushort8*>(t + (size_t)s7 * F + f0);
#pragma unroll
      for (int j = 0; j < 8; ++j) {
        float p0 = bf2f(u0[j]) + bf2f(u1[j]);
        float p1 = bf2f(u2[j]) + bf2f(u3[j]);
        float p2 = bf2f(u4[j]) + bf2f(u5[j]);
        float p3 = bf2f(u6[j]) + bf2f(u7[j]);
        acc[j] += (p0 + p1) + (p2 + p3);
      }
    }
    if (e + 4 <= e1) {
      int s0 = col[e], s1 = col[e + 1], s2 = col[e + 2], s3 = col[e + 3];
      ushort8 u0 = *reinterpret_cast<const ushort8*>(t + (size_t)s0 * F + f0);
      ushort8 u1 = *reinterpret_cast<const ushort8*>(t + (size_t)s1 * F + f0);
      ushort8 u2 = *reinterpret_cast<const ushort8*>(t + (size_t)s2 * F + f0);
      ushort8 u3 = *reinterpret_cast<const ushort8*>(t + (size_t)s3 * F + f0);
#pragma unroll
      for (int j = 0; j < 8; ++j)
        acc[j] += (bf2f(u0[j]) + bf2f(u1[j])) + (bf2f(u2[j]) + bf2f(u3[j]));
      e += 4;
    }
    if (e + 2 <= e1) {
      int s0 = col[e], s1 = col[e + 1];
      ushort8 u0 = *reinterpret_cast<const ushort8*>(t + (size_t)s0 * F + f0);
      ushort8 u1 = *reinterpret_cast<const ushort8*>(t + (size_t)s1 * F + f0);
#pragma unroll
      for (int j = 0; j < 8; ++j) acc[j] += bf2f(u0[j]) + bf2f(u1[j]);
      e += 2;
    }
    if (e < e1) {
      int s = col[e];
      ushort8 u = *reinterpret_cast<const ushort8*>(t + (size_t)s * F + f0);
#pragma unroll
      for (int j = 0; j < 8; ++j) acc[j] += bf2f(u[j]);
    }
#pragma unroll
    for (int j = 0; j < 8; ++j) v[j] = fmaxf(acc[j] * di + bias[f0 + j], 0.f);
    if (OUT_F32) {
      float* o = (float*)outp;
#pragma unroll
      for (int j = 0; j < 8; j += 4) {
        f32x4 w = {v[j], v[j + 1], v[j + 2], v[j + 3]};
        __builtin_nontemporal_store(w, reinterpret_cast<f32x4*>(o + (size_t)r * F + f0 + j));
      }
    } else {
      ushort8 ov;
#pragma unroll
      for (int j = 0; j < 8; ++j) ov[j] = f2bf(v[j]);
      *reinterpret_cast<ushort8*>((unsigned short*)outp + (size_t)r * F + f0) = ov;
    }
  }
  if (STATS) {
    __shared__ float sA[256 * 8];
    __shared__ float sB[256 * 8];
#pragma unroll
    for (int j = 0; j < 8; ++j) { sA[threadIdx.x * 8 + j] = v[j]; sB[threadIdx.x * 8 + j] = v[j] * v[j]; }
    __syncthreads();
    if (threadIdx.x < 128) {
      int f = threadIdx.x;
      int cc = f >> 3, jj = f & 7;
      float s = 0.f, q = 0.f;
#pragma unroll
      for (int gg = 0; gg < 16; ++gg) {
        s += sA[(gg * 16 + cc) * 8 + jj];
        q += sB[(gg * 16 + cc) * 8 + jj];
      }
      float* bk = bank + (blockIdx.x & (NBANK - 1)) * 256;
      atomicAdd(&bk[f], s);
      atomicAdd(&bk[128 + f], q);
    }
  }
}

// ---------------- batchnorm finalize ----------------
__global__ void k_bnfinal(const float* __restrict__ bank, const float* __restrict__ gamma,
                          const float* __restrict__ beta, float* __restrict__ ss, float invN) {
  int f = threadIdx.x;   // 128 threads
  float s = 0.f, q = 0.f;
  for (int b = 0; b < NBANK; ++b) { s += bank[b * 256 + f]; q += bank[b * 256 + 128 + f]; }
  float m = s * invN;
  float var = q * invN - m * m;
  float sc = gamma[f] * rsqrtf(var + BN_EPS);
  ss[f] = sc;
  ss[128 + f] = beta[f] - m * sc;
}

// ---------------- launch ----------------
extern "C" void kernel_launch(void* const* d_in, const int* in_sizes, int n_in,
                              void* d_out, int out_size, void* d_ws, size_t ws_size,
                              hipStream_t stream) {
  const float* x    = (const float*)d_in[0];
  const int*   ei   = (const int*)d_in[1];
  const float* W1   = (const float*)d_in[2];
  const float* b1   = (const float*)d_in[3];
  const float* W2   = (const float*)d_in[4];
  const float* b2   = (const float*)d_in[5];
  const float* Wout = (const float*)d_in[6];
  const float* bout = (const float*)d_in[7];
  const float* gamma= (const float*)d_in[8];
  const float* beta = (const float*)d_in[9];
  float* out = (float*)d_out;

  const int n = in_sizes[0] / 128;
  const int e = in_sizes[1] / 2;
  const int* src = ei;
  const int* dst = ei + e;
  const int nb = (n + 127) >> 7;
  const int epb = (e + NBLK - 1) / NBLK;

  char* ws = (char*)d_ws;
  size_t off = 0;
  auto alloc = [&](size_t bytes) -> void* {
    void* p = ws + off;
    off += (bytes + 255) & ~(size_t)255;
    return p;
  };
  int*   pairsG = (int*)alloc((size_t)NBLK * epb * 4);
  int*   cntT   = (int*)alloc((size_t)NBLK * 1024 * 4);
  int*   scanT  = (int*)alloc((size_t)NBLK * 1024 * 4);
  int*   totals = (int*)alloc(1024 * 4);
  int*   bbase  = (int*)alloc(1025 * 4);
  int*   rowptr = (int*)alloc(((size_t)n + 1) * 4);
  float* dinv   = (float*)alloc((size_t)n * 4);
  int*   col    = (int*)alloc((size_t)e * 4);
  float* bank1  = (float*)alloc(NBANK * 256 * 4);
  float* bank2  = (float*)alloc(NBANK * 256 * 4);
  float* ss1    = (float*)alloc(256 * 4);
  float* ss2    = (float*)alloc(256 * 4);
  unsigned short* Wt1 = (unsigned short*)alloc(128 * 128 * 2);
  unsigned short* Wt2 = (unsigned short*)alloc(128 * 128 * 2);
  unsigned short* Wt3 = (unsigned short*)alloc(384 * 64 * 2);
  unsigned short* t   = (unsigned short*)alloc((size_t)n * 128 * 2);
  unsigned short* a1  = (unsigned short*)alloc((size_t)n * 128 * 2);
  unsigned short* a2  = (unsigned short*)alloc((size_t)n * 128 * 2);

  hipMemsetAsync(bank1, 0, (size_t)NBANK * 256 * 4 * 2, stream);

  // graph build
  k_part<<<NBLK, 256, 0, stream>>>(src, dst, e, epb, pairsG, cntT, scanT);
  k_btot<<<nb, 256, 0, stream>>>(cntT, totals);
  k_bscan<<<1, 1024, 0, stream>>>(totals, bbase, nb, e);
  k_build<<<nb, 256, 0, stream>>>(pairsG, cntT, scanT, bbase, epb, n, nb, rowptr, col, dinv);
  k_cvtw<<<224, 256, 0, stream>>>(W1, W2, Wout, Wt1, Wt2, Wt3);

  int nbG = (n + 127) / 128;
  int nbA128 = (n + 15) / 16;
  int nbA64 = (n + 31) / 32;
  float invN = 1.f / (float)n;

  // layer 1
  k_gemm128<0><<<nbG, 256, 0, stream>>>(x, Wt1, nullptr, dinv, t, n);
  k_agg<128, 1, 0><<<nbA128, 256, 0, stream>>>(t, rowptr, col, dinv, b1, a1, bank1, n);
  k_bnfinal<<<1, 128, 0, stream>>>(bank1, gamma, beta, ss1, invN);

  // layer 2
  k_gemm128<1><<<nbG, 256, 0, stream>>>(a1, Wt2, ss1, dinv, t, n);
  k_agg<128, 1, 0><<<nbA128, 256, 0, stream>>>(t, rowptr, col, dinv, b2, a2, bank2, n);
  k_bnfinal<<<1, 128, 0, stream>>>(bank2, gamma, beta, ss2, invN);

  // layer 3
  k_gemm3<<<nbG, 256, 0, stream>>>(x, a1, a2, ss1, ss2, Wt3, dinv, t, n);
  k_agg<64, 0, 1><<<nbA64, 256, 0, stream>>>(t, rowptr, col, dinv, bout, out, nullptr, n);
}

// Round 5
// 273.611 us; speedup vs baseline: 3.7256x; 1.1070x over previous
//
#include <hip/hip_runtime.h>
#include <cstdint>
#include <cstddef>

#define BN_EPS 1e-5f
#define NBLK 256
#define EPBMAX 6400
#define BCAP 4096
#define NBANK 32

typedef __attribute__((ext_vector_type(8))) short  bf16x8;
typedef __attribute__((ext_vector_type(4))) float  f32x4;
typedef __attribute__((ext_vector_type(8))) unsigned short ushort8;

__device__ __forceinline__ float bf2f(unsigned short u) {
  union { unsigned int i; float f; } c; c.i = ((unsigned int)u) << 16; return c.f;
}
__device__ __forceinline__ unsigned short f2bf(float f) {
  union { float f; unsigned int i; } c; c.f = f;
  unsigned int u = c.i;
  return (unsigned short)((u + 0x7FFFu + ((u >> 16) & 1u)) >> 16);  // RNE
}

// ---------------- graph partition (+ fused weight-convert blocks) ----------------
__global__ __launch_bounds__(256) void k_part(const int* __restrict__ src, const int* __restrict__ dst, int e, int epb,
                                              int* __restrict__ pairsG, int* __restrict__ cntT, int* __restrict__ scanT,
                                              int* __restrict__ totals,
                                              const float* __restrict__ W1, const float* __restrict__ W2,
                                              const float* __restrict__ W3,
                                              unsigned short* __restrict__ Wt1, unsigned short* __restrict__ Wt2,
                                              unsigned short* __restrict__ Wt3) {
  int b = blockIdx.x, tid = threadIdx.x;
  if (b >= NBLK) {           // fused cvtw: f32 [K][N] -> bf16 [N][K]
    int bb = b - NBLK;
    if (bb < 64)       { int idx = bb * 256 + tid;        Wt1[(idx & 127) * 128 + (idx >> 7)] = f2bf(W1[idx]); }
    else if (bb < 128) { int idx = (bb - 64) * 256 + tid; Wt2[(idx & 127) * 128 + (idx >> 7)] = f2bf(W2[idx]); }
    else               { int idx = (bb - 128) * 256 + tid; Wt3[(idx & 63) * 384 + (idx >> 6)] = f2bf(W3[idx]); }
    return;
  }
  __shared__ int sbuf[EPBMAX];
  __shared__ int hist[1024];
  __shared__ int base[1024];
  __shared__ int tmp[256];
  int e0 = b * epb, e1 = min(e0 + epb, e);
  for (int i = tid; i < 1024; i += 256) hist[i] = 0;
  __syncthreads();
  for (int i = e0 + tid; i < e1; i += 256) atomicAdd(&hist[dst[i] >> 7], 1);
  __syncthreads();
  // bucket totals -> global (replaces k_btot; totals pre-zeroed by memset)
  for (int i = tid; i < 1024; i += 256) { int h = hist[i]; if (h) atomicAdd(&totals[i], h); }
  int c0 = hist[tid * 4], c1 = hist[tid * 4 + 1], c2 = hist[tid * 4 + 2], c3 = hist[tid * 4 + 3];
  int lsum = c0 + c1 + c2 + c3;
  tmp[tid] = lsum; __syncthreads();
  for (int off = 1; off < 256; off <<= 1) {
    int t = (tid >= off) ? tmp[tid - off] : 0; __syncthreads();
    tmp[tid] += t; __syncthreads();
  }
  int excl = tmp[tid] - lsum;
  base[tid * 4] = excl; base[tid * 4 + 1] = excl + c0;
  base[tid * 4 + 2] = excl + c0 + c1; base[tid * 4 + 3] = excl + c0 + c1 + c2;
  *(int4*)(cntT + b * 1024 + tid * 4) = make_int4(c0, c1, c2, c3);
  *(int4*)(scanT + b * 1024 + tid * 4) = make_int4(base[tid * 4], base[tid * 4 + 1], base[tid * 4 + 2], base[tid * 4 + 3]);
  __syncthreads();
  for (int i = e0 + tid; i < e1; i += 256) {
    int d = dst[i], s = src[i];
    int p = atomicAdd(&base[d >> 7], 1);
    sbuf[p] = ((d & 127) << 25) | s;
  }
  __syncthreads();
  int cnt = e1 - e0;
  for (int i = tid; i < cnt; i += 256) pairsG[e0 + i] = sbuf[i];
}

__global__ __launch_bounds__(1024) void k_bscan(const int* __restrict__ totals, int* __restrict__ bbase, int nb, int e) {
  __shared__ int tmp[1024];
  int tid = threadIdx.x;
  int v = (tid < nb) ? totals[tid] : 0;
  tmp[tid] = v; __syncthreads();
  for (int off = 1; off < 1024; off <<= 1) {
    int t = (tid >= off) ? tmp[tid - off] : 0; __syncthreads();
    tmp[tid] += t; __syncthreads();
  }
  if (tid < nb) bbase[tid] = tmp[tid] - v;
  if (tid == 0) bbase[nb] = e;
}

__global__ __launch_bounds__(256) void k_build(const int* __restrict__ pairsG, const int* __restrict__ cntT,
                                               const int* __restrict__ scanT, const int* __restrict__ bbase_,
                                               int epb, int n, int nb,
                                               int* __restrict__ rowptr, int* __restrict__ colG, float* __restrict__ dinvG) {
  __shared__ int lpair[BCAP];
  __shared__ int lcol[BCAP];
  __shared__ int lcnt[128], lcur[128];
  __shared__ int tmp[256];
  int k = blockIdx.x, tid = threadIdx.x;
  int len = cntT[tid * 1024 + k];
  int sbase = tid * epb + scanT[tid * 1024 + k];
  tmp[tid] = len; __syncthreads();
  for (int off = 1; off < 256; off <<= 1) {
    int t = (tid >= off) ? tmp[tid - off] : 0; __syncthreads();
    tmp[tid] += t; __syncthreads();
  }
  int dpos = tmp[tid] - len;
  int cnt = tmp[255];
  for (int i = 0; i < len; ++i) lpair[dpos + i] = pairsG[sbase + i];
  if (tid < 128) lcnt[tid] = 0;
  __syncthreads();
  for (int j = tid; j < cnt; j += 256) atomicAdd(&lcnt[((unsigned)lpair[j]) >> 25], 1);
  __syncthreads();
  if (tid < 128) tmp[tid] = lcnt[tid];
  __syncthreads();
  for (int off = 1; off < 128; off <<= 1) {
    int t = (tid >= off && tid < 128) ? tmp[tid - off] : 0; __syncthreads();
    if (tid < 128) tmp[tid] += t;
    __syncthreads();
  }
  int bb = bbase_[k];
  if (tid < 128) {
    int excl = tmp[tid] - lcnt[tid];
    lcur[tid] = excl;
    int g = k * 128 + tid;
    if (g < n) {
      rowptr[g] = bb + excl;
      dinvG[g] = rsqrtf((float)lcnt[tid] + 1.0f);
    }
  }
  if (k == nb - 1 && tid == 0) rowptr[n] = bb + cnt;
  __syncthreads();
  for (int j = tid; j < cnt; j += 256) {
    int w = lpair[j];
    int p = atomicAdd(&lcur[((unsigned)w) >> 25], 1);
    lcol[p] = w & 0x01FFFFFF;
  }
  __syncthreads();
  for (int j = tid; j < cnt; j += 256) colG[bb + j] = lcol[j];
}

// ---------------- MFMA GEMM: C[n,128](bf16) = dinv[r]*(A @ Wt^T), K=128 ----------------
// A fragments loaded DIRECT from global (no A LDS). MODE 0: f32 src. MODE 1: bf16 src + fused BN
// (scale/shift computed in-block from stat banks). B staged in LDS with XOR swizzle.
template <int MODE>
__global__ __launch_bounds__(256) void k_gemm128(const void* __restrict__ Ap, const unsigned short* __restrict__ Bt,
                                                 const float* __restrict__ bank, const float* __restrict__ gamma,
                                                 const float* __restrict__ beta, float invN,
                                                 const float* __restrict__ dinv, unsigned short* __restrict__ C, int n) {
  __shared__ unsigned short Bs[128 * 128];
  __shared__ float ssl[256];
  const int tid = threadIdx.x;
  const int row0 = blockIdx.x * 128;
  if (MODE == 1 && tid < 128) {     // fused bnfinal (redundant per block, L2-hot)
    float s = 0.f, q = 0.f;
    for (int b = 0; b < NBANK; ++b) { s += bank[b * 256 + tid]; q += bank[b * 256 + 128 + tid]; }
    float m = s * invN, var = q * invN - m * m;
    float sc = gamma[tid] * rsqrtf(var + BN_EPS);
    ssl[tid] = sc; ssl[128 + tid] = beta[tid] - m * sc;
  }
  {
    int colr = tid >> 1;
    int cbase = (tid & 1) * 8;
#pragma unroll
    for (int i = 0; i < 8; ++i) {
      int c16 = (cbase + i) * 16;
      int dstb = colr * 256 + (c16 ^ ((colr & 7) << 4));
      ushort8 v = *reinterpret_cast<const ushort8*>(Bt + colr * 128 + (c16 >> 1));
      *reinterpret_cast<ushort8*>((char*)Bs + dstb) = v;
    }
  }
  __syncthreads();

  const int wv = tid >> 6, l = tid & 63, lr = l & 15, lk = l >> 4;
  int rowc[2];
#pragma unroll
  for (int mi = 0; mi < 2; ++mi) {
    int gr = row0 + wv * 32 + mi * 16 + lr;
    rowc[mi] = (gr < n) ? gr : 0;    // clamp to avoid OOB fault; result masked at write
  }

  bf16x8 aF[2][4];
  if (MODE == 0) {
    const float* A = (const float*)Ap;
#pragma unroll
    for (int mi = 0; mi < 2; ++mi)
#pragma unroll
      for (int kt = 0; kt < 4; ++kt) {
        const float* p = A + (size_t)rowc[mi] * 128 + kt * 32 + lk * 8;
        f32x4 lo = *reinterpret_cast<const f32x4*>(p);
        f32x4 hi = *reinterpret_cast<const f32x4*>(p + 4);
        bf16x8 a;
#pragma unroll
        for (int j = 0; j < 4; ++j) { a[j] = (short)f2bf(lo[j]); a[4 + j] = (short)f2bf(hi[j]); }
        aF[mi][kt] = a;
      }
  } else {
    const unsigned short* A = (const unsigned short*)Ap;
    ushort8 raw[2][4];
#pragma unroll
    for (int mi = 0; mi < 2; ++mi)
#pragma unroll
      for (int kt = 0; kt < 4; ++kt)
        raw[mi][kt] = *reinterpret_cast<const ushort8*>(A + (size_t)rowc[mi] * 128 + kt * 32 + lk * 8);
#pragma unroll
    for (int kt = 0; kt < 4; ++kt) {
      int kof = kt * 32 + lk * 8;
      float sc[8], sh[8];
#pragma unroll
      for (int j = 0; j < 8; ++j) { sc[j] = ssl[kof + j]; sh[j] = ssl[128 + kof + j]; }
#pragma unroll
      for (int mi = 0; mi < 2; ++mi) {
        bf16x8 a;
#pragma unroll
        for (int j = 0; j < 8; ++j) a[j] = (short)f2bf(bf2f(raw[mi][kt][j]) * sc[j] + sh[j]);
        aF[mi][kt] = a;
      }
    }
  }

  f32x4 acc[2][8];
#pragma unroll
  for (int mi = 0; mi < 2; ++mi)
#pragma unroll
    for (int ni = 0; ni < 8; ++ni) acc[mi][ni] = (f32x4)0.f;

#pragma unroll
  for (int kt = 0; kt < 4; ++kt) {
    int kbyte = kt * 64 + lk * 16;
    bf16x8 bF[8];
#pragma unroll
    for (int ni = 0; ni < 8; ++ni) {
      int c = ni * 16 + lr;
      bF[ni] = *reinterpret_cast<bf16x8*>((char*)Bs + c * 256 + (kbyte ^ ((c & 7) << 4)));
    }
#pragma unroll
    for (int mi = 0; mi < 2; ++mi)
#pragma unroll
      for (int ni = 0; ni < 8; ++ni)
        acc[mi][ni] = __builtin_amdgcn_mfma_f32_16x16x32_bf16(aF[mi][kt], bF[ni], acc[mi][ni], 0, 0, 0);
  }

#pragma unroll
  for (int mi = 0; mi < 2; ++mi) {
#pragma unroll
    for (int i = 0; i < 4; ++i) {
      int gr = row0 + wv * 32 + mi * 16 + lk * 4 + i;
      if (gr < n) {
        float di = dinv[gr];
#pragma unroll
        for (int ni = 0; ni < 8; ++ni) {
          int gc = ni * 16 + lr;
          C[(size_t)gr * 128 + gc] = f2bf(acc[mi][ni][i] * di);
        }
      }
    }
  }
}

// ---------------- MFMA GEMM3: C[n,64](bf16) = dinv*([x | bn(a1) | bn(a2)] @ Wt3^T), K=384 ----------------
__global__ __launch_bounds__(256) void k_gemm3(const float* __restrict__ x, const unsigned short* __restrict__ a1,
                                               const unsigned short* __restrict__ a2,
                                               const float* __restrict__ bank1, const float* __restrict__ bank2,
                                               const float* __restrict__ gamma, const float* __restrict__ beta,
                                               float invN,
                                               const unsigned short* __restrict__ Bt3, const float* __restrict__ dinv,
                                               unsigned short* __restrict__ C, int n) {
  __shared__ unsigned short Bs[64 * 384];   // 48KB
  __shared__ float ssl[512];                // [sc1|sh1|sc2|sh2]
  const int tid = threadIdx.x;
  const int row0 = blockIdx.x * 128;
  if (tid < 256) {
    int f = tid & 127;
    const float* bk = (tid < 128) ? bank1 : bank2;
    int base = (tid < 128) ? 0 : 256;
    float s = 0.f, q = 0.f;
    for (int b = 0; b < NBANK; ++b) { s += bk[b * 256 + f]; q += bk[b * 256 + 128 + f]; }
    float m = s * invN, var = q * invN - m * m;
    float sc = gamma[f] * rsqrtf(var + BN_EPS);
    ssl[base + f] = sc; ssl[base + 128 + f] = beta[f] - m * sc;
  }
  {
    int colr = tid >> 2;
    int cb = tid & 3;
#pragma unroll
    for (int i = 0; i < 12; ++i) {
      int c16 = (cb + 4 * i) * 16;
      int dstb = colr * 768 + (c16 ^ ((colr & 7) << 4));
      ushort8 v = *reinterpret_cast<const ushort8*>(Bt3 + colr * 384 + (c16 >> 1));
      *reinterpret_cast<ushort8*>((char*)Bs + dstb) = v;
    }
  }
  __syncthreads();

  const int wv = tid >> 6, l = tid & 63, lr = l & 15, lk = l >> 4;
  int rowc[2];
#pragma unroll
  for (int mi = 0; mi < 2; ++mi) {
    int gr = row0 + wv * 32 + mi * 16 + lr;
    rowc[mi] = (gr < n) ? gr : 0;
  }

  f32x4 acc[2][4];
#pragma unroll
  for (int mi = 0; mi < 2; ++mi)
#pragma unroll
    for (int ni = 0; ni < 4; ++ni) acc[mi][ni] = (f32x4)0.f;

#pragma unroll
  for (int ch = 0; ch < 3; ++ch) {
    bf16x8 aF[2][4];
    if (ch == 0) {
#pragma unroll
      for (int mi = 0; mi < 2; ++mi)
#pragma unroll
        for (int kt = 0; kt < 4; ++kt) {
          const float* p = x + (size_t)rowc[mi] * 128 + kt * 32 + lk * 8;
          f32x4 lo = *reinterpret_cast<const f32x4*>(p);
          f32x4 hi = *reinterpret_cast<const f32x4*>(p + 4);
          bf16x8 a;
#pragma unroll
          for (int j = 0; j < 4; ++j) { a[j] = (short)f2bf(lo[j]); a[4 + j] = (short)f2bf(hi[j]); }
          aF[mi][kt] = a;
        }
    } else {
      const unsigned short* A = (ch == 1) ? a1 : a2;
      int base = (ch == 1) ? 0 : 256;
      ushort8 raw[2][4];
#pragma unroll
      for (int mi = 0; mi < 2; ++mi)
#pragma unroll
        for (int kt = 0; kt < 4; ++kt)
          raw[mi][kt] = *reinterpret_cast<const ushort8*>(A + (size_t)rowc[mi] * 128 + kt * 32 + lk * 8);
#pragma unroll
      for (int kt = 0; kt < 4; ++kt) {
        int kof = kt * 32 + lk * 8;
        float sc[8], sh[8];
#pragma unroll
        for (int j = 0; j < 8; ++j) { sc[j] = ssl[base + kof + j]; sh[j] = ssl[base + 128 + kof + j]; }
#pragma unroll
        for (int mi = 0; mi < 2; ++mi) {
          bf16x8 a;
#pragma unroll
          for (int j = 0; j < 8; ++j) a[j] = (short)f2bf(bf2f(raw[mi][kt][j]) * sc[j] + sh[j]);
          aF[mi][kt] = a;
        }
      }
    }
#pragma unroll
    for (int kt = 0; kt < 4; ++kt) {
      int kbyteB = ch * 256 + kt * 64 + lk * 16;
      bf16x8 bF[4];
#pragma unroll
      for (int ni = 0; ni < 4; ++ni) {
        int c = ni * 16 + lr;
        bF[ni] = *reinterpret_cast<bf16x8*>((char*)Bs + c * 768 + (kbyteB ^ ((c & 7) << 4)));
      }
#pragma unroll
      for (int mi = 0; mi < 2; ++mi)
#pragma unroll
        for (int ni = 0; ni < 4; ++ni)
          acc[mi][ni] = __builtin_amdgcn_mfma_f32_16x16x32_bf16(aF[mi][kt], bF[ni], acc[mi][ni], 0, 0, 0);
    }
  }

#pragma unroll
  for (int mi = 0; mi < 2; ++mi) {
#pragma unroll
    for (int i = 0; i < 4; ++i) {
      int gr = row0 + wv * 32 + mi * 16 + lk * 4 + i;
      if (gr < n) {
        float di = dinv[gr];
#pragma unroll
        for (int ni = 0; ni < 4; ++ni) {
          int gc = ni * 16 + lr;
          C[(size_t)gr * 64 + gc] = f2bf(acc[mi][ni][i] * di);
        }
      }
    }
  }
}

// ---------------- aggregation (unchanged; at random-gather roofline) ----------------
template <int F, int STATS, int OUT_F32>
__global__ __launch_bounds__(256) void k_agg(const unsigned short* __restrict__ t, const int* __restrict__ rowptr,
                                             const int* __restrict__ col, const float* __restrict__ dinv,
                                             const float* __restrict__ bias, void* __restrict__ outp,
                                             float* __restrict__ bank, int n) {
  const int G = F / 8;
  const int RPB = 256 / G;
  int g = threadIdx.x / G;
  int c = threadIdx.x % G;
  int r = blockIdx.x * RPB + g;
  bool act = (r < n);
  float v[8];
#pragma unroll
  for (int j = 0; j < 8; ++j) v[j] = 0.f;
  int f0 = c * 8;
  if (act) {
    float di = dinv[r];
    int e = rowptr[r];
    int e1 = rowptr[r + 1];
    float acc[8];
    {
      ushort8 sv = *reinterpret_cast<const ushort8*>(t + (size_t)r * F + f0);
#pragma unroll
      for (int j = 0; j < 8; ++j) acc[j] = bf2f(sv[j]);
    }
    for (; e + 8 <= e1; e += 8) {
      int s0 = col[e],     s1 = col[e + 1], s2 = col[e + 2], s3 = col[e + 3];
      int s4 = col[e + 4], s5 = col[e + 5], s6 = col[e + 6], s7 = col[e + 7];
      ushort8 u0 = *reinterpret_cast<const ushort8*>(t + (size_t)s0 * F + f0);
      ushort8 u1 = *reinterpret_cast<const ushort8*>(t + (size_t)s1 * F + f0);
      ushort8 u2 = *reinterpret_cast<const ushort8*>(t + (size_t)s2 * F + f0);
      ushort8 u3 = *reinterpret_cast<const ushort8*>(t + (size_t)s3 * F + f0);
      ushort8 u4 = *reinterpret_cast<const ushort8*>(t + (size_t)s4 * F + f0);
      ushort8 u5 = *reinterpret_cast<const ushort8*>(t + (size_t)s5 * F + f0);
      ushort8 u6 = *reinterpret_cast<const ushort8*>(t + (size_t)s6 * F + f0);
      ushort8 u7 = *reinterpret_cast<const ushort8*>(t + (size_t)s7 * F + f0);
#pragma unroll
      for (int j = 0; j < 8; ++j) {
        float p0 = bf2f(u0[j]) + bf2f(u1[j]);
        float p1 = bf2f(u2[j]) + bf2f(u3[j]);
        float p2 = bf2f(u4[j]) + bf2f(u5[j]);
        float p3 = bf2f(u6[j]) + bf2f(u7[j]);
        acc[j] += (p0 + p1) + (p2 + p3);
      }
    }
    if (e + 4 <= e1) {
      int s0 = col[e], s1 = col[e + 1], s2 = col[e + 2], s3 = col[e + 3];
      ushort8 u0 = *reinterpret_cast<const ushort8*>(t + (size_t)s0 * F + f0);
      ushort8 u1 = *reinterpret_cast<const ushort8*>(t + (size_t)s1 * F + f0);
      ushort8 u2 = *reinterpret_cast<const ushort8*>(t + (size_t)s2 * F + f0);
      ushort8 u3 = *reinterpret_cast<const ushort8*>(t + (size_t)s3 * F + f0);
#pragma unroll
      for (int j = 0; j < 8; ++j)
        acc[j] += (bf2f(u0[j]) + bf2f(u1[j])) + (bf2f(u2[j]) + bf2f(u3[j]));
      e += 4;
    }
    if (e + 2 <= e1) {
      int s0 = col[e], s1 = col[e + 1];
      ushort8 u0 = *reinterpret_cast<const ushort8*>(t + (size_t)s0 * F + f0);
      ushort8 u1 = *reinterpret_cast<const ushort8*>(t + (size_t)s1 * F + f0);
#pragma unroll
      for (int j = 0; j < 8; ++j) acc[j] += bf2f(u0[j]) + bf2f(u1[j]);
      e += 2;
    }
    if (e < e1) {
      int s = col[e];
      ushort8 u = *reinterpret_cast<const ushort8*>(t + (size_t)s * F + f0);
#pragma unroll
      for (int j = 0; j < 8; ++j) acc[j] += bf2f(u[j]);
    }
#pragma unroll
    for (int j = 0; j < 8; ++j) v[j] = fmaxf(acc[j] * di + bias[f0 + j], 0.f);
    if (OUT_F32) {
      float* o = (float*)outp;
#pragma unroll
      for (int j = 0; j < 8; j += 4) {
        f32x4 w = {v[j], v[j + 1], v[j + 2], v[j + 3]};
        __builtin_nontemporal_store(w, reinterpret_cast<f32x4*>(o + (size_t)r * F + f0 + j));
      }
    } else {
      ushort8 ov;
#pragma unroll
      for (int j = 0; j < 8; ++j) ov[j] = f2bf(v[j]);
      *reinterpret_cast<ushort8*>((unsigned short*)outp + (size_t)r * F + f0) = ov;
    }
  }
  if (STATS) {
    __shared__ float sA[256 * 8];
    __shared__ float sB[256 * 8];
#pragma unroll
    for (int j = 0; j < 8; ++j) { sA[threadIdx.x * 8 + j] = v[j]; sB[threadIdx.x * 8 + j] = v[j] * v[j]; }
    __syncthreads();
    if (threadIdx.x < 128) {
      int f = threadIdx.x;
      int cc = f >> 3, jj = f & 7;
      float s = 0.f, q = 0.f;
#pragma unroll
      for (int gg = 0; gg < 16; ++gg) {
        s += sA[(gg * 16 + cc) * 8 + jj];
        q += sB[(gg * 16 + cc) * 8 + jj];
      }
      float* bk = bank + (blockIdx.x & (NBANK - 1)) * 256;
      atomicAdd(&bk[f], s);
      atomicAdd(&bk[128 + f], q);
    }
  }
}

// ---------------- launch ----------------
extern "C" void kernel_launch(void* const* d_in, const int* in_sizes, int n_in,
                              void* d_out, int out_size, void* d_ws, size_t ws_size,
                              hipStream_t stream) {
  const float* x    = (const float*)d_in[0];
  const int*   ei   = (const int*)d_in[1];
  const float* W1   = (const float*)d_in[2];
  const float* b1   = (const float*)d_in[3];
  const float* W2   = (const float*)d_in[4];
  const float* b2   = (const float*)d_in[5];
  const float* Wout = (const float*)d_in[6];
  const float* bout = (const float*)d_in[7];
  const float* gamma= (const float*)d_in[8];
  const float* beta = (const float*)d_in[9];
  float* out = (float*)d_out;

  const int n = in_sizes[0] / 128;
  const int e = in_sizes[1] / 2;
  const int* src = ei;
  const int* dst = ei + e;
  const int nb = (n + 127) >> 7;
  const int epb = (e + NBLK - 1) / NBLK;

  char* ws = (char*)d_ws;
  size_t off = 0;
  auto alloc = [&](size_t bytes) -> void* {
    void* p = ws + off;
    off += (bytes + 255) & ~(size_t)255;
    return p;
  };
  int*   pairsG = (int*)alloc((size_t)NBLK * epb * 4);
  int*   cntT   = (int*)alloc((size_t)NBLK * 1024 * 4);
  int*   scanT  = (int*)alloc((size_t)NBLK * 1024 * 4);
  int*   totals = (int*)alloc(1024 * 4);          // totals+bank1+bank2 contiguous: one memset
  float* bank1  = (float*)alloc(NBANK * 256 * 4);
  float* bank2  = (float*)alloc(NBANK * 256 * 4);
  int*   bbase  = (int*)alloc(1025 * 4);
  int*   rowptr = (int*)alloc(((size_t)n + 1) * 4);
  float* dinv   = (float*)alloc((size_t)n * 4);
  int*   col    = (int*)alloc((size_t)e * 4);
  unsigned short* Wt1 = (unsigned short*)alloc(128 * 128 * 2);
  unsigned short* Wt2 = (unsigned short*)alloc(128 * 128 * 2);
  unsigned short* Wt3 = (unsigned short*)alloc(384 * 64 * 2);
  unsigned short* t   = (unsigned short*)alloc((size_t)n * 128 * 2);
  unsigned short* a1  = (unsigned short*)alloc((size_t)n * 128 * 2);
  unsigned short* a2  = (unsigned short*)alloc((size_t)n * 128 * 2);

  hipMemsetAsync(totals, 0, 1024 * 4 + (size_t)2 * NBANK * 256 * 4, stream);

  // graph build (+fused weight convert)
  k_part<<<NBLK + 224, 256, 0, stream>>>(src, dst, e, epb, pairsG, cntT, scanT, totals,
                                         W1, W2, Wout, Wt1, Wt2, Wt3);
  k_bscan<<<1, 1024, 0, stream>>>(totals, bbase, nb, e);
  k_build<<<nb, 256, 0, stream>>>(pairsG, cntT, scanT, bbase, epb, n, nb, rowptr, col, dinv);

  int nbG = (n + 127) / 128;
  int nbA128 = (n + 15) / 16;
  int nbA64 = (n + 31) / 32;
  float invN = 1.f / (float)n;

  // layer 1
  k_gemm128<0><<<nbG, 256, 0, stream>>>(x, Wt1, nullptr, nullptr, nullptr, invN, dinv, t, n);
  k_agg<128, 1, 0><<<nbA128, 256, 0, stream>>>(t, rowptr, col, dinv, b1, a1, bank1, n);

  // layer 2 (BN of h1 fused into A-load)
  k_gemm128<1><<<nbG, 256, 0, stream>>>(a1, Wt2, bank1, gamma, beta, invN, dinv, t, n);
  k_agg<128, 1, 0><<<nbA128, 256, 0, stream>>>(t, rowptr, col, dinv, b2, a2, bank2, n);

  // layer 3 (both BNs fused into A-load)
  k_gemm3<<<nbG, 256, 0, stream>>>(x, a1, a2, bank1, bank2, gamma, beta, invN, Wt3, dinv, t, n);
  k_agg<64, 0, 1><<<nbA64, 256, 0, stream>>>(t, rowptr, col, dinv, bout, out, nullptr, n);
}